// Round 1
// baseline (888.942 us; speedup 1.0000x reference)
//
#include <hip/hip_runtime.h>
#include <math.h>

#define NN 50000
#define EE 800000
#define IN_DIM 256
#define HID 64
#define HEADS 4
#define OUT_DIM 128

__device__ __forceinline__ float lrelu(float v){ return v > 0.f ? v : 0.2f * v; }

// ---------------- CSR build ----------------
__global__ void k_hist(const int* __restrict__ dst, int* __restrict__ cnt, int E){
  int i = blockIdx.x * blockDim.x + threadIdx.x;
  if (i < E) atomicAdd(&cnt[dst[i]], 1);
}

__global__ __launch_bounds__(1024) void k_scan(const int* __restrict__ cnt, int* __restrict__ rowptr, int n){
  __shared__ int sd[1024];
  __shared__ int s_carry;
  if (threadIdx.x == 0) s_carry = 0;
  __syncthreads();
  for (int base = 0; base < n; base += 1024){
    int i = base + threadIdx.x;
    int v = (i < n) ? cnt[i] : 0;
    sd[threadIdx.x] = v;
    __syncthreads();
    for (int off = 1; off < 1024; off <<= 1){
      int t = (threadIdx.x >= off) ? sd[threadIdx.x - off] : 0;
      __syncthreads();
      sd[threadIdx.x] += t;
      __syncthreads();
    }
    int carry = s_carry;
    if (i < n) rowptr[i] = carry + sd[threadIdx.x] - v;   // exclusive
    __syncthreads();
    if (threadIdx.x == 0) s_carry = carry + sd[1023];
    __syncthreads();
  }
  if (threadIdx.x == 0) rowptr[n] = s_carry;
}

__global__ void k_scatter(const int* __restrict__ dst, const int* __restrict__ rowptr,
                          int* __restrict__ cursor, int* __restrict__ eid, int E){
  int i = blockIdx.x * blockDim.x + threadIdx.x;
  if (i < E){ int d = dst[i]; int p = rowptr[d] + atomicAdd(&cursor[d], 1); eid[p] = i; }
}

// ---------------- fp32 GEMM: C[M,N] = A[M,K] @ B[K,N] ----------------
#define BM 64
#define BN 64
#define BK 16
__global__ __launch_bounds__(256) void k_sgemm(const float* __restrict__ A, const float* __restrict__ B,
                                               float* __restrict__ C, int M, int K, int N){
  __shared__ __align__(16) float As[BK][68];   // stride 68 floats = 272B (16B aligned rows)
  __shared__ __align__(16) float Bs[BK][BN];
  int tid = threadIdx.x;
  int tx = tid & 15, ty = tid >> 4;
  int bm = blockIdx.y * BM, bn = blockIdx.x * BN;
  float acc[4][4] = {};
  int la_m = tid >> 2, la_k = (tid & 3) << 2;   // A: row la_m (0..63), cols la_k..+3
  int lb_k = tid >> 4, lb_n = (tid & 15) << 2;  // B: row lb_k (0..15), cols lb_n..+3
  bool arow_ok = (bm + la_m) < M;
  const float* Aptr = A + (size_t)(bm + la_m) * K + la_k;
  for (int k0 = 0; k0 < K; k0 += BK){
    float4 av = arow_ok ? *(const float4*)(Aptr + k0) : make_float4(0.f,0.f,0.f,0.f);
    float4 bv = *(const float4*)(B + (size_t)(k0 + lb_k) * N + bn + lb_n);
    As[la_k+0][la_m] = av.x; As[la_k+1][la_m] = av.y;
    As[la_k+2][la_m] = av.z; As[la_k+3][la_m] = av.w;
    *(float4*)&Bs[lb_k][lb_n] = bv;
    __syncthreads();
    #pragma unroll
    for (int kk = 0; kk < BK; ++kk){
      float4 a4 = *(const float4*)&As[kk][ty*4];
      float4 b4 = *(const float4*)&Bs[kk][tx*4];
      acc[0][0] += a4.x*b4.x; acc[0][1] += a4.x*b4.y; acc[0][2] += a4.x*b4.z; acc[0][3] += a4.x*b4.w;
      acc[1][0] += a4.y*b4.x; acc[1][1] += a4.y*b4.y; acc[1][2] += a4.y*b4.z; acc[1][3] += a4.y*b4.w;
      acc[2][0] += a4.z*b4.x; acc[2][1] += a4.z*b4.y; acc[2][2] += a4.z*b4.z; acc[2][3] += a4.z*b4.w;
      acc[3][0] += a4.w*b4.x; acc[3][1] += a4.w*b4.y; acc[3][2] += a4.w*b4.z; acc[3][3] += a4.w*b4.w;
    }
    __syncthreads();
  }
  #pragma unroll
  for (int i = 0; i < 4; ++i){
    int row = bm + ty*4 + i;
    if (row < M){
      float4 o = make_float4(acc[i][0], acc[i][1], acc[i][2], acc[i][3]);
      *(float4*)&C[(size_t)row * N + bn + tx*4] = o;
    }
  }
}

// ---------------- layer1 el/er: block=256, one node per block ----------------
__global__ void k_elr1(const float* __restrict__ feat, const float* __restrict__ al,
                       const float* __restrict__ ar, float* __restrict__ el, float* __restrict__ er){
  int n = blockIdx.x, t = threadIdx.x;
  float x = feat[(size_t)n*256 + t];
  float pl = x * al[t], pr = x * ar[t];
  #pragma unroll
  for (int off = 32; off; off >>= 1){ pl += __shfl_down(pl, off); pr += __shfl_down(pr, off); }
  if ((t & 63) == 0){ int h = t >> 6; el[n*4 + h] = pl; er[n*4 + h] = pr; }
}

// ---------------- layer1 per-edge e ----------------
__global__ void k_edge1(const int* __restrict__ src, const int* __restrict__ dst,
                        const float* __restrict__ el, const float* __restrict__ er,
                        float* __restrict__ e, int E){
  int i = blockIdx.x * blockDim.x + threadIdx.x;
  if (i >= E) return;
  float4 l = *(const float4*)&el[src[i]*4];
  float4 r = *(const float4*)&er[dst[i]*4];
  float4 o;
  o.x = lrelu(l.x + r.x); o.y = lrelu(l.y + r.y);
  o.z = lrelu(l.z + r.z); o.w = lrelu(l.w + r.w);
  *(float4*)&e[(size_t)i*4] = o;
}

// ---------------- layer1 per-node max + 1/denom (wave per (node,head)) ----------------
__global__ void k_maxden1(const int* __restrict__ rowptr, const int* __restrict__ eid,
                          const float* __restrict__ e, float* __restrict__ emax, float* __restrict__ rden){
  int n = blockIdx.x;
  int h = threadIdx.x >> 6, lane = threadIdx.x & 63;
  int b = rowptr[n], deg = rowptr[n+1] - b;
  float m = -INFINITY;
  for (int j = lane; j < deg; j += 64) m = fmaxf(m, e[(size_t)eid[b+j]*4 + h]);
  #pragma unroll
  for (int off = 32; off; off >>= 1) m = fmaxf(m, __shfl_down(m, off));
  m = __shfl(m, 0);
  float s = 0.f;
  for (int j = lane; j < deg; j += 64) s += expf(e[(size_t)eid[b+j]*4 + h] - m);
  #pragma unroll
  for (int off = 32; off; off >>= 1) s += __shfl_down(s, off);
  if (lane == 0){ emax[n*4 + h] = m; rden[n*4 + h] = (deg > 0) ? 1.0f / s : 0.0f; }
}

// ---------------- layer1 per-edge alpha (in place over e) ----------------
__global__ void k_alpha1(const int* __restrict__ dst, float* __restrict__ e,
                         const float* __restrict__ emax, const float* __restrict__ rden, int E){
  int i = blockIdx.x * blockDim.x + threadIdx.x;
  if (i >= E) return;
  int d = dst[i];
  float4 ev = *(const float4*)&e[(size_t)i*4];
  float4 m  = *(const float4*)&emax[d*4];
  float4 rd = *(const float4*)&rden[d*4];
  ev.x = expf(ev.x - m.x) * rd.x; ev.y = expf(ev.y - m.y) * rd.y;
  ev.z = expf(ev.z - m.z) * rd.z; ev.w = expf(ev.w - m.w) * rd.w;
  *(float4*)&e[(size_t)i*4] = ev;
}

// ---------------- layer1 aggregate + ELU (block=256 per node) ----------------
__global__ __launch_bounds__(256) void k_agg1(const int* __restrict__ rowptr, const int* __restrict__ eid,
                                              const int* __restrict__ src, const float* __restrict__ alpha,
                                              const float* __restrict__ feat, float* __restrict__ h1){
  int n = blockIdx.x, t = threadIdx.x, h = t >> 6;
  int b = rowptr[n], deg = rowptr[n+1] - b;
  float acc = 0.f;
  for (int j = 0; j < deg; ++j){
    int ed = eid[b + j];
    int s = src[ed];
    float a = alpha[(size_t)ed*4 + h];
    acc += a * feat[(size_t)s*256 + t];
  }
  h1[(size_t)n*256 + t] = (acc > 0.f) ? acc : expm1f(acc);
}

// ---------------- layer2 el/er (block=64, one node) ----------------
__global__ void k_elr2(const float* __restrict__ feat, const float* __restrict__ al,
                       const float* __restrict__ ar, float* __restrict__ el, float* __restrict__ er){
  int n = blockIdx.x, t = threadIdx.x;
  float x0 = feat[(size_t)n*128 + t], x1 = feat[(size_t)n*128 + 64 + t];
  float pl = x0*al[t] + x1*al[64+t];
  float pr = x0*ar[t] + x1*ar[64+t];
  #pragma unroll
  for (int off = 32; off; off >>= 1){ pl += __shfl_down(pl, off); pr += __shfl_down(pr, off); }
  if (t == 0){ el[n] = pl; er[n] = pr; }
}

__global__ void k_edge2(const int* __restrict__ src, const int* __restrict__ dst,
                        const float* __restrict__ el, const float* __restrict__ er,
                        float* __restrict__ e, int E){
  int i = blockIdx.x * blockDim.x + threadIdx.x;
  if (i >= E) return;
  e[i] = lrelu(el[src[i]] + er[dst[i]]);
}

// wave per node: block 256 = 4 nodes
__global__ void k_maxden2(const int* __restrict__ rowptr, const int* __restrict__ eid,
                          const float* __restrict__ e, float* __restrict__ emax, float* __restrict__ rden, int Nn){
  int n = blockIdx.x*4 + (threadIdx.x >> 6);
  int lane = threadIdx.x & 63;
  if (n >= Nn) return;
  int b = rowptr[n], deg = rowptr[n+1] - b;
  float m = -INFINITY;
  for (int j = lane; j < deg; j += 64) m = fmaxf(m, e[eid[b+j]]);
  #pragma unroll
  for (int off = 32; off; off >>= 1) m = fmaxf(m, __shfl_down(m, off));
  m = __shfl(m, 0);
  float s = 0.f;
  for (int j = lane; j < deg; j += 64) s += expf(e[eid[b+j]] - m);
  #pragma unroll
  for (int off = 32; off; off >>= 1) s += __shfl_down(s, off);
  if (lane == 0){ emax[n] = m; rden[n] = (deg > 0) ? 1.0f / s : 0.0f; }
}

__global__ void k_alpha2(const int* __restrict__ dst, float* __restrict__ e,
                         const float* __restrict__ emax, const float* __restrict__ rden, int E){
  int i = blockIdx.x * blockDim.x + threadIdx.x;
  if (i >= E) return;
  int d = dst[i];
  e[i] = expf(e[i] - emax[d]) * rden[d];
}

__global__ __launch_bounds__(128) void k_agg2(const int* __restrict__ rowptr, const int* __restrict__ eid,
                                              const int* __restrict__ src, const float* __restrict__ alpha,
                                              const float* __restrict__ feat, float* __restrict__ out){
  int n = blockIdx.x, t = threadIdx.x;
  int b = rowptr[n], deg = rowptr[n+1] - b;
  float acc = 0.f;
  for (int j = 0; j < deg; ++j){
    int ed = eid[b + j];
    int s = src[ed];
    acc += alpha[ed] * feat[(size_t)s*128 + t];
  }
  out[(size_t)n*128 + t] = acc;
}

// ---------------- host launch ----------------
static inline size_t align256(size_t x){ return (x + 255) & ~(size_t)255; }

extern "C" void kernel_launch(void* const* d_in, const int* in_sizes, int n_in,
                              void* d_out, int out_size, void* d_ws, size_t ws_size,
                              hipStream_t stream){
  const float* h_in   = (const float*)d_in[0];
  const int*   src    = (const int*)d_in[1];
  const int*   dst    = (const int*)d_in[2];
  const float* W1     = (const float*)d_in[3];
  const float* al1    = (const float*)d_in[4];
  const float* ar1    = (const float*)d_in[5];
  const float* W2     = (const float*)d_in[6];
  const float* al2    = (const float*)d_in[7];
  const float* ar2    = (const float*)d_in[8];
  float* out = (float*)d_out;

  char* ws = (char*)d_ws;
  size_t off = 0;
  float* feat1 = (float*)(ws + off); off = align256(off + (size_t)NN*256*4);   // also feat2
  float* h1    = (float*)(ws + off); off = align256(off + (size_t)NN*256*4);
  float* e1    = (float*)(ws + off); off = align256(off + (size_t)EE*4*4);     // also e2/alpha2
  float* el1   = (float*)(ws + off); off = align256(off + (size_t)NN*4*4);     // also el2
  float* er1   = (float*)(ws + off); off = align256(off + (size_t)NN*4*4);
  float* emax1 = (float*)(ws + off); off = align256(off + (size_t)NN*4*4);
  float* rden1 = (float*)(ws + off); off = align256(off + (size_t)NN*4*4);
  int* rowptr  = (int*)(ws + off);   off = align256(off + (size_t)(NN+1)*4);
  int* cnt     = (int*)(ws + off);   off = align256(off + (size_t)NN*4);       // also cursor
  int* eid     = (int*)(ws + off);   off = align256(off + (size_t)EE*4);
  if (off > ws_size) return;  // workspace too small: fail loudly (output stays poisoned)

  float* feat2 = feat1;
  float* el2 = el1; float* er2 = er1; float* emax2 = emax1; float* rden2 = rden1;
  float* e2 = e1;

  const int EB = (EE + 255)/256;

  // CSR build
  hipMemsetAsync(cnt, 0, (size_t)NN*4, stream);
  k_hist<<<EB, 256, 0, stream>>>(dst, cnt, EE);
  k_scan<<<1, 1024, 0, stream>>>(cnt, rowptr, NN);
  hipMemsetAsync(cnt, 0, (size_t)NN*4, stream);
  k_scatter<<<EB, 256, 0, stream>>>(dst, rowptr, cnt, eid, EE);

  // ----- layer 1 -----
  k_sgemm<<<dim3(256/BN, (NN+BM-1)/BM), 256, 0, stream>>>(h_in, W1, feat1, NN, 256, 256);
  k_elr1<<<NN, 256, 0, stream>>>(feat1, al1, ar1, el1, er1);
  k_edge1<<<EB, 256, 0, stream>>>(src, dst, el1, er1, e1, EE);
  k_maxden1<<<NN, 256, 0, stream>>>(rowptr, eid, e1, emax1, rden1);
  k_alpha1<<<EB, 256, 0, stream>>>(dst, e1, emax1, rden1, EE);
  k_agg1<<<NN, 256, 0, stream>>>(rowptr, eid, src, e1, feat1, h1);

  // ----- layer 2 -----
  k_sgemm<<<dim3(128/BN, (NN+BM-1)/BM), 256, 0, stream>>>(h1, W2, feat2, NN, 256, 128);
  k_elr2<<<NN, 64, 0, stream>>>(feat2, al2, ar2, el2, er2);
  k_edge2<<<EB, 256, 0, stream>>>(src, dst, el2, er2, e2, EE);
  k_maxden2<<<(NN+3)/4, 256, 0, stream>>>(rowptr, eid, e2, emax2, rden2, NN);
  k_alpha2<<<EB, 256, 0, stream>>>(dst, e2, emax2, rden2, EE);
  k_agg2<<<NN, 128, 0, stream>>>(rowptr, eid, src, e2, feat2, out);
}

// Round 2
// 565.911 us; speedup vs baseline: 1.5708x; 1.5708x over previous
//
#include <hip/hip_runtime.h>
#include <math.h>

#define NN 50000
#define EE 800000
#define MAXC 256   // softmax/aggregate chunk size (deg<=256 -> single chunk)

__device__ __forceinline__ float lrelu(float v){ return v > 0.f ? v : 0.2f * v; }

// ---------------- CSR build ----------------
__global__ void k_hist(const int* __restrict__ dst, int* __restrict__ cnt, int E){
  int i = blockIdx.x * blockDim.x + threadIdx.x;
  if (i < E) atomicAdd(&cnt[dst[i]], 1);
}

__global__ __launch_bounds__(1024) void k_scan(const int* __restrict__ cnt, int* __restrict__ rowptr, int n){
  __shared__ int wsum[16];
  __shared__ int s_carry;
  int t = threadIdx.x, w = t >> 6, lane = t & 63;
  if (t == 0) s_carry = 0;
  __syncthreads();
  for (int base = 0; base < n; base += 1024){
    int i = base + t;
    int v = (i < n) ? cnt[i] : 0;
    int x = v;
    #pragma unroll
    for (int off = 1; off < 64; off <<= 1){ int y = __shfl_up(x, off); if (lane >= off) x += y; }
    if (lane == 63) wsum[w] = x;
    __syncthreads();
    if (t < 16){
      int y = wsum[t];
      #pragma unroll
      for (int off = 1; off < 16; off <<= 1){ int z = __shfl_up(y, off); if (t >= off) y += z; }
      wsum[t] = y;
    }
    __syncthreads();
    int carry = s_carry;
    int woff = (w > 0) ? wsum[w-1] : 0;
    if (i < n) rowptr[i] = carry + woff + x - v;   // exclusive
    __syncthreads();
    if (t == 1023) s_carry = carry + wsum[15];
    __syncthreads();
  }
  if (t == 0) rowptr[n] = s_carry;
}

__global__ void k_scatter(const int* __restrict__ src, const int* __restrict__ dst,
                          const int* __restrict__ rowptr, int* __restrict__ cursor,
                          int* __restrict__ csr_src, int E){
  int i = blockIdx.x * blockDim.x + threadIdx.x;
  if (i < E){ int d = dst[i]; int p = rowptr[d] + atomicAdd(&cursor[d], 1); csr_src[p] = src[i]; }
}

// ---------------- fp32 GEMM: C[M,N] = A[M,K] @ B[K,N] ----------------
#define BM 64
#define BN 64
#define BK 16
__global__ __launch_bounds__(256) void k_sgemm(const float* __restrict__ A, const float* __restrict__ B,
                                               float* __restrict__ C, int M, int K, int N){
  __shared__ __align__(16) float As[BK][68];
  __shared__ __align__(16) float Bs[BK][BN];
  int tid = threadIdx.x;
  int tx = tid & 15, ty = tid >> 4;
  int bm = blockIdx.y * BM, bn = blockIdx.x * BN;
  float acc[4][4] = {};
  int la_m = tid >> 2, la_k = (tid & 3) << 2;
  int lb_k = tid >> 4, lb_n = (tid & 15) << 2;
  bool arow_ok = (bm + la_m) < M;
  const float* Aptr = A + (size_t)(bm + la_m) * K + la_k;
  for (int k0 = 0; k0 < K; k0 += BK){
    float4 av = arow_ok ? *(const float4*)(Aptr + k0) : make_float4(0.f,0.f,0.f,0.f);
    float4 bv = *(const float4*)(B + (size_t)(k0 + lb_k) * N + bn + lb_n);
    As[la_k+0][la_m] = av.x; As[la_k+1][la_m] = av.y;
    As[la_k+2][la_m] = av.z; As[la_k+3][la_m] = av.w;
    *(float4*)&Bs[lb_k][lb_n] = bv;
    __syncthreads();
    #pragma unroll
    for (int kk = 0; kk < BK; ++kk){
      float4 a4 = *(const float4*)&As[kk][ty*4];
      float4 b4 = *(const float4*)&Bs[kk][tx*4];
      acc[0][0] += a4.x*b4.x; acc[0][1] += a4.x*b4.y; acc[0][2] += a4.x*b4.z; acc[0][3] += a4.x*b4.w;
      acc[1][0] += a4.y*b4.x; acc[1][1] += a4.y*b4.y; acc[1][2] += a4.y*b4.z; acc[1][3] += a4.y*b4.w;
      acc[2][0] += a4.z*b4.x; acc[2][1] += a4.z*b4.y; acc[2][2] += a4.z*b4.z; acc[2][3] += a4.z*b4.w;
      acc[3][0] += a4.w*b4.x; acc[3][1] += a4.w*b4.y; acc[3][2] += a4.w*b4.z; acc[3][3] += a4.w*b4.w;
    }
    __syncthreads();
  }
  #pragma unroll
  for (int i = 0; i < 4; ++i){
    int row = bm + ty*4 + i;
    if (row < M){
      float4 o = make_float4(acc[i][0], acc[i][1], acc[i][2], acc[i][3]);
      *(float4*)&C[(size_t)row * N + bn + tx*4] = o;
    }
  }
}

// ---------------- el/er projections ----------------
__global__ void k_elr1(const float* __restrict__ feat, const float* __restrict__ al,
                       const float* __restrict__ ar, float* __restrict__ el, float* __restrict__ er){
  int n = blockIdx.x, t = threadIdx.x;
  float x = feat[(size_t)n*256 + t];
  float pl = x * al[t], pr = x * ar[t];
  #pragma unroll
  for (int off = 32; off; off >>= 1){ pl += __shfl_down(pl, off); pr += __shfl_down(pr, off); }
  if ((t & 63) == 0){ int h = t >> 6; el[n*4 + h] = pl; er[n*4 + h] = pr; }
}

__global__ void k_elr2(const float* __restrict__ feat, const float* __restrict__ al,
                       const float* __restrict__ ar, float* __restrict__ el, float* __restrict__ er){
  int n = blockIdx.x, t = threadIdx.x;
  float x0 = feat[(size_t)n*128 + t], x1 = feat[(size_t)n*128 + 64 + t];
  float pl = x0*al[t] + x1*al[64+t];
  float pr = x0*ar[t] + x1*ar[64+t];
  #pragma unroll
  for (int off = 32; off; off >>= 1){ pl += __shfl_down(pl, off); pr += __shfl_down(pr, off); }
  if (t == 0){ el[n] = pl; er[n] = pr; }
}

// ---------------- fused edge-softmax + aggregate, layer 1 (H=4, D=64/head) ----------------
// block = 256 (4 waves), one dst node per block. Flash-style online softmax over
// chunks of MAXC edges -> correct for any degree. Aggregation: one wave per edge,
// lane reads float4 -> 1KB coalesced row load, 4 rows in flight per block.
__global__ __launch_bounds__(256) void k_fused1(
    const int* __restrict__ rowptr, const int* __restrict__ csr_src,
    const float* __restrict__ el, const float* __restrict__ er,
    const float* __restrict__ feat, float* __restrict__ h1)
{
  __shared__ __align__(16) float e_sh[MAXC*4];   // e, then p in place
  __shared__ int s_sh[MAXC];
  __shared__ float m_sh[4], s_sum[4], scale_sh[4];
  __shared__ __align__(16) float part[4][256];
  int n = blockIdx.x;
  int t = threadIdx.x, w = t >> 6, lane = t & 63;
  int h = lane >> 4;                    // head owned by this lane in row-read mode
  int b = rowptr[n], deg = rowptr[n+1] - b;
  if (t < 4){ m_sh[t] = -INFINITY; s_sum[t] = 0.f; }
  float4 er4 = *(const float4*)&er[n*4];
  float4 acc = make_float4(0.f,0.f,0.f,0.f);
  __syncthreads();

  for (int c0 = 0; c0 < deg; c0 += MAXC){
    int C = min(MAXC, deg - c0);
    // 1) per-edge e (gather el4[src], 800KB table -> L2-resident)
    if (t < C){
      int si = csr_src[b + c0 + t];
      s_sh[t] = si;
      float4 l4 = *(const float4*)&el[si*4];
      float4 e4;
      e4.x = lrelu(l4.x + er4.x); e4.y = lrelu(l4.y + er4.y);
      e4.z = lrelu(l4.z + er4.z); e4.w = lrelu(l4.w + er4.w);
      *(float4*)&e_sh[t*4] = e4;
    }
    __syncthreads();
    // 2) chunk max per head (wave w handles head w)
    float mc = -INFINITY;
    for (int j = lane; j < C; j += 64) mc = fmaxf(mc, e_sh[j*4 + w]);
    #pragma unroll
    for (int off = 32; off; off >>= 1) mc = fmaxf(mc, __shfl_down(mc, off));
    if (lane == 0){
      float mo = m_sh[w], mn = fmaxf(mo, mc);
      scale_sh[w] = __expf(mo - mn);
      m_sh[w] = mn;
    }
    __syncthreads();
    // 3) p = exp(e - m'), chunk sum per head; rescale running sum + acc
    float mn = m_sh[w], sc = 0.f;
    for (int j = lane; j < C; j += 64){
      float pv = __expf(e_sh[j*4 + w] - mn);
      e_sh[j*4 + w] = pv;
      sc += pv;
    }
    #pragma unroll
    for (int off = 32; off; off >>= 1) sc += __shfl_down(sc, off);
    if (lane == 0) s_sum[w] = s_sum[w]*scale_sh[w] + sc;
    float asc = scale_sh[h];
    acc.x *= asc; acc.y *= asc; acc.z *= asc; acc.w *= asc;
    __syncthreads();
    // 4) aggregate: wave w takes edges j = w, w+4, ... ; full 1KB row per wave
    for (int j = w; j < C; j += 4){
      int si = s_sh[j];
      float a = e_sh[j*4 + h];
      float4 f = ((const float4*)(feat + (size_t)si*256))[lane];
      acc.x += a*f.x; acc.y += a*f.y; acc.z += a*f.z; acc.w += a*f.w;
    }
    __syncthreads();
  }
  // combine wave partials, normalize, ELU
  *(float4*)&part[w][lane*4] = acc;
  __syncthreads();
  float v = 0.f;
  if (deg > 0){
    v = part[0][t] + part[1][t] + part[2][t] + part[3][t];
    v /= s_sum[t >> 6];
    v = (v > 0.f) ? v : expm1f(v);
  }
  h1[(size_t)n*256 + t] = v;
}

// ---------------- fused edge-softmax + aggregate, layer 2 (H=1, D=128) ----------------
__global__ __launch_bounds__(256) void k_fused2(
    const int* __restrict__ rowptr, const int* __restrict__ csr_src,
    const float* __restrict__ el, const float* __restrict__ er,
    const float* __restrict__ feat, float* __restrict__ out)
{
  __shared__ float e_sh[MAXC];
  __shared__ int s_sh[MAXC];
  __shared__ float m_sh, s_sum, scale_sh;
  __shared__ __align__(16) float part[4][128];
  int n = blockIdx.x;
  int t = threadIdx.x, w = t >> 6, lane = t & 63;
  int b = rowptr[n], deg = rowptr[n+1] - b;
  if (t == 0){ m_sh = -INFINITY; s_sum = 0.f; }
  float er_n = er[n];
  float2 acc = make_float2(0.f, 0.f);
  __syncthreads();

  for (int c0 = 0; c0 < deg; c0 += MAXC){
    int C = min(MAXC, deg - c0);
    if (t < C){
      int si = csr_src[b + c0 + t];
      s_sh[t] = si;
      e_sh[t] = lrelu(el[si] + er_n);
    }
    __syncthreads();
    if (w == 0){
      float mc = -INFINITY;
      for (int j = lane; j < C; j += 64) mc = fmaxf(mc, e_sh[j]);
      #pragma unroll
      for (int off = 32; off; off >>= 1) mc = fmaxf(mc, __shfl_down(mc, off));
      if (lane == 0){
        float mo = m_sh, mn = fmaxf(mo, mc);
        scale_sh = __expf(mo - mn);
        m_sh = mn;
      }
    }
    __syncthreads();
    if (w == 0){
      float mn = m_sh, sc = 0.f;
      for (int j = lane; j < C; j += 64){
        float pv = __expf(e_sh[j] - mn);
        e_sh[j] = pv;
        sc += pv;
      }
      #pragma unroll
      for (int off = 32; off; off >>= 1) sc += __shfl_down(sc, off);
      if (lane == 0) s_sum = s_sum*scale_sh + sc;
    }
    float asc = scale_sh;          // written before previous barrier
    acc.x *= asc; acc.y *= asc;
    __syncthreads();
    for (int j = w; j < C; j += 4){
      int si = s_sh[j];
      float a = e_sh[j];
      float2 f = ((const float2*)(feat + (size_t)si*128))[lane];
      acc.x += a*f.x; acc.y += a*f.y;
    }
    __syncthreads();
  }
  *(float2*)&part[w][lane*2] = acc;
  __syncthreads();
  if (t < 128){
    float v = 0.f;
    if (deg > 0){
      v = part[0][t] + part[1][t] + part[2][t] + part[3][t];
      v /= s_sum;
    }
    out[(size_t)n*128 + t] = v;
  }
}

// ---------------- host launch ----------------
static inline size_t align256(size_t x){ return (x + 255) & ~(size_t)255; }

extern "C" void kernel_launch(void* const* d_in, const int* in_sizes, int n_in,
                              void* d_out, int out_size, void* d_ws, size_t ws_size,
                              hipStream_t stream){
  const float* h_in = (const float*)d_in[0];
  const int*   src  = (const int*)d_in[1];
  const int*   dst  = (const int*)d_in[2];
  const float* W1   = (const float*)d_in[3];
  const float* al1  = (const float*)d_in[4];
  const float* ar1  = (const float*)d_in[5];
  const float* W2   = (const float*)d_in[6];
  const float* al2  = (const float*)d_in[7];
  const float* ar2  = (const float*)d_in[8];
  float* out = (float*)d_out;

  char* ws = (char*)d_ws;
  size_t off = 0;
  float* feat1   = (float*)(ws + off); off = align256(off + (size_t)NN*256*4);  // reused as feat2
  float* h1      = (float*)(ws + off); off = align256(off + (size_t)NN*256*4);
  float* el1     = (float*)(ws + off); off = align256(off + (size_t)NN*4*4);    // reused as el2
  float* er1     = (float*)(ws + off); off = align256(off + (size_t)NN*4*4);    // reused as er2
  int* rowptr    = (int*)(ws + off);   off = align256(off + (size_t)(NN+1)*4);
  int* cnt       = (int*)(ws + off);   off = align256(off + (size_t)NN*4);
  int* csr_src   = (int*)(ws + off);   off = align256(off + (size_t)EE*4);
  if (off > ws_size) return;  // fail loudly: output stays poisoned

  float* feat2 = feat1;
  float* el2 = el1; float* er2 = er1;

  const int EB = (EE + 255)/256;

  // CSR build (dst-sorted edges, src stored directly in CSR order)
  hipMemsetAsync(cnt, 0, (size_t)NN*4, stream);
  k_hist<<<EB, 256, 0, stream>>>(dst, cnt, EE);
  k_scan<<<1, 1024, 0, stream>>>(cnt, rowptr, NN);
  hipMemsetAsync(cnt, 0, (size_t)NN*4, stream);
  k_scatter<<<EB, 256, 0, stream>>>(src, dst, rowptr, cnt, csr_src, EE);

  // ----- layer 1 -----
  k_sgemm<<<dim3(256/BN, (NN+BM-1)/BM), 256, 0, stream>>>(h_in, W1, feat1, NN, 256, 256);
  k_elr1<<<NN, 256, 0, stream>>>(feat1, al1, ar1, el1, er1);
  k_fused1<<<NN, 256, 0, stream>>>(rowptr, csr_src, el1, er1, feat1, h1);

  // ----- layer 2 -----
  k_sgemm<<<dim3(128/BN, (NN+BM-1)/BM), 256, 0, stream>>>(h1, W2, feat2, NN, 256, 128);
  k_elr2<<<NN, 64, 0, stream>>>(feat2, al2, ar2, el2, er2);
  k_fused2<<<NN, 256, 0, stream>>>(rowptr, csr_src, el2, er2, feat2, out);
}

// Round 3
// 485.760 us; speedup vs baseline: 1.8300x; 1.1650x over previous
//
#include <hip/hip_runtime.h>
#include <math.h>

#define NN 50000
#define EE 800000

__device__ __forceinline__ float lrelu(float v){ return v > 0.f ? v : 0.2f * v; }
__device__ __forceinline__ float sel4(float4 v, int h){
  return h == 0 ? v.x : h == 1 ? v.y : h == 2 ? v.z : v.w;
}

// ---------------- CSR build ----------------
__global__ void k_hist(const int* __restrict__ dst, int* __restrict__ cnt, int E){
  int i = blockIdx.x * blockDim.x + threadIdx.x;
  if (i < E) atomicAdd(&cnt[dst[i]], 1);
}

// 4 elements/thread, chunks of 4096
__global__ __launch_bounds__(1024) void k_scan(const int* __restrict__ cnt, int* __restrict__ rowptr, int n){
  __shared__ int wsum[16];
  __shared__ int s_carry;
  int t = threadIdx.x, w = t >> 6, lane = t & 63;
  if (t == 0) s_carry = 0;
  __syncthreads();
  for (int base = 0; base < n; base += 4096){
    int i0 = base + t*4;
    int v0=0,v1=0,v2=0,v3=0;
    if (i0 + 3 < n){ int4 v = *(const int4*)&cnt[i0]; v0=v.x; v1=v.y; v2=v.z; v3=v.w; }
    else {
      if (i0+0 < n) v0 = cnt[i0+0];
      if (i0+1 < n) v1 = cnt[i0+1];
      if (i0+2 < n) v2 = cnt[i0+2];
      if (i0+3 < n) v3 = cnt[i0+3];
    }
    int tot = v0+v1+v2+v3;
    int x = tot;
    #pragma unroll
    for (int off = 1; off < 64; off <<= 1){ int y = __shfl_up(x, off); if (lane >= off) x += y; }
    if (lane == 63) wsum[w] = x;
    __syncthreads();
    if (t < 16){
      int y = wsum[t];
      #pragma unroll
      for (int off = 1; off < 16; off <<= 1){ int z = __shfl_up(y, off); if (t >= off) y += z; }
      wsum[t] = y;
    }
    __syncthreads();
    int carry = s_carry;
    int woff = (w > 0) ? wsum[w-1] : 0;
    int ex = carry + woff + x - tot;   // exclusive prefix at i0
    if (i0+0 < n) rowptr[i0+0] = ex;
    if (i0+1 < n) rowptr[i0+1] = ex + v0;
    if (i0+2 < n) rowptr[i0+2] = ex + v0 + v1;
    if (i0+3 < n) rowptr[i0+3] = ex + v0 + v1 + v2;
    __syncthreads();
    if (t == 1023) s_carry = carry + wsum[15];
    __syncthreads();
  }
  if (t == 0) rowptr[n] = s_carry;
}

__global__ void k_scatter(const int* __restrict__ src, const int* __restrict__ dst,
                          const int* __restrict__ rowptr, int* __restrict__ cursor,
                          int* __restrict__ csr_src, int E){
  int i = blockIdx.x * blockDim.x + threadIdx.x;
  if (i < E){ int d = dst[i]; int p = rowptr[d] + atomicAdd(&cursor[d], 1); csr_src[p] = src[i]; }
}

// ---------------- fp32 GEMM: C[M,N] = A[M,K] @ B[K,N], 128x128 tile, 8x8/thread ----------------
#define GBM 128
#define GBN 128
#define GBK 16
__global__ __launch_bounds__(256) void k_sgemm(const float* __restrict__ A, const float* __restrict__ B,
                                               float* __restrict__ C, int M, int K, int N){
  __shared__ __align__(16) float As[GBK][GBM];   // [k][m]
  __shared__ __align__(16) float Bs[GBK][GBN];   // [k][n]
  int tid = threadIdx.x;
  int tx = tid & 15, ty = tid >> 4;
  int bm = blockIdx.y * GBM, bn = blockIdx.x * GBN;
  float acc[8][8] = {};
  // staging indices
  int ar = tid >> 2;            // 0..63 (rows ar, ar+64)
  int ak = (tid & 3) * 4;       // k-offset 0,4,8,12
  int br = tid >> 4;            // 0..15
  int bc = (tid & 15) * 4;      // 0..60 (cols bc, bc+64)
  bool a0ok = (bm + ar) < M, a1ok = (bm + ar + 64) < M;
  const float* A0 = A + (size_t)(bm + ar) * K + ak;
  const float* A1 = A + (size_t)(bm + ar + 64) * K + ak;
  const float* B0 = B + (size_t)br * N + bn + bc;

  for (int k0 = 0; k0 < K; k0 += GBK){
    float4 a0 = a0ok ? *(const float4*)(A0 + k0) : make_float4(0,0,0,0);
    float4 a1 = a1ok ? *(const float4*)(A1 + k0) : make_float4(0,0,0,0);
    float4 b0 = *(const float4*)(B0 + (size_t)k0 * N);
    float4 b1 = *(const float4*)(B0 + (size_t)k0 * N + 64);
    As[ak+0][ar] = a0.x; As[ak+1][ar] = a0.y; As[ak+2][ar] = a0.z; As[ak+3][ar] = a0.w;
    As[ak+0][ar+64] = a1.x; As[ak+1][ar+64] = a1.y; As[ak+2][ar+64] = a1.z; As[ak+3][ar+64] = a1.w;
    *(float4*)&Bs[br][bc] = b0;
    *(float4*)&Bs[br][bc+64] = b1;
    __syncthreads();
    #pragma unroll
    for (int kk = 0; kk < GBK; ++kk){
      float aR[8], bR[8];
      *(float4*)&aR[0] = *(const float4*)&As[kk][ty*4];
      *(float4*)&aR[4] = *(const float4*)&As[kk][64 + ty*4];
      *(float4*)&bR[0] = *(const float4*)&Bs[kk][tx*4];
      *(float4*)&bR[4] = *(const float4*)&Bs[kk][64 + tx*4];
      #pragma unroll
      for (int i = 0; i < 8; ++i)
        #pragma unroll
        for (int j = 0; j < 8; ++j)
          acc[i][j] = fmaf(aR[i], bR[j], acc[i][j]);
    }
    __syncthreads();
  }
  #pragma unroll
  for (int i = 0; i < 8; ++i){
    int row = bm + ((i < 4) ? (ty*4 + i) : (64 + ty*4 + i - 4));
    if (row < M){
      *(float4*)&C[(size_t)row * N + bn + tx*4]      = *(float4*)&acc[i][0];
      *(float4*)&C[(size_t)row * N + bn + 64 + tx*4] = *(float4*)&acc[i][4];
    }
  }
}

// ---------------- el/er projections ----------------
__global__ void k_elr1(const float* __restrict__ feat, const float* __restrict__ al,
                       const float* __restrict__ ar, float* __restrict__ el, float* __restrict__ er){
  int n = blockIdx.x, t = threadIdx.x;
  float x = feat[(size_t)n*256 + t];
  float pl = x * al[t], pr = x * ar[t];
  #pragma unroll
  for (int off = 32; off; off >>= 1){ pl += __shfl_down(pl, off); pr += __shfl_down(pr, off); }
  if ((t & 63) == 0){ int h = t >> 6; el[n*4 + h] = pl; er[n*4 + h] = pr; }
}

__global__ void k_elr2(const float* __restrict__ feat, const float* __restrict__ al,
                       const float* __restrict__ ar, float* __restrict__ el, float* __restrict__ er){
  int n = blockIdx.x, t = threadIdx.x;
  float x0 = feat[(size_t)n*128 + t], x1 = feat[(size_t)n*128 + 64 + t];
  float pl = x0*al[t] + x1*al[64+t];
  float pr = x0*ar[t] + x1*ar[64+t];
  #pragma unroll
  for (int off = 32; off; off >>= 1){ pl += __shfl_down(pl, off); pr += __shfl_down(pr, off); }
  if (t == 0){ el[n] = pl; er[n] = pr; }
}

// ---------------- fused softmax+aggregate, layer 1: ONE WAVE PER NODE ----------------
// 4 waves/block, no __syncthreads. Lane j holds edge j (chunks of 64 for deg>64).
// Aggregation: per edge one wave-wide 1KB row load; alpha/src via per-wave LDS slice.
__global__ __launch_bounds__(256) void k_fused1(
    const int* __restrict__ rowptr, const int* __restrict__ csr_src,
    const float* __restrict__ el, const float* __restrict__ er,
    const float* __restrict__ feat, float* __restrict__ h1)
{
  __shared__ __align__(16) float p_sh[4][64*4];
  __shared__ int si_sh[4][64];
  int w = threadIdx.x >> 6, lane = threadIdx.x & 63;
  int n = blockIdx.x*4 + w;
  if (n >= NN) return;
  int b = rowptr[n], deg = rowptr[n+1] - b;
  int h = lane >> 4;                       // head for this lane's acc/agg columns
  float4 er4 = *(const float4*)&er[n*4];
  float4 m4 = make_float4(-INFINITY,-INFINITY,-INFINITY,-INFINITY);
  float4 s4 = make_float4(0,0,0,0);
  float4 acc = make_float4(0,0,0,0);

  for (int c0 = 0; c0 < deg; c0 += 64){
    int C = min(64, deg - c0);
    int si = 0;
    float4 e4 = make_float4(-INFINITY,-INFINITY,-INFINITY,-INFINITY);
    if (lane < C){
      si = csr_src[b + c0 + lane];
      float4 l4 = *(const float4*)&el[si*4];
      e4.x = lrelu(l4.x + er4.x); e4.y = lrelu(l4.y + er4.y);
      e4.z = lrelu(l4.z + er4.z); e4.w = lrelu(l4.w + er4.w);
    }
    // wave max per head (all lanes end with the max)
    float4 mc = e4;
    #pragma unroll
    for (int off = 32; off; off >>= 1){
      mc.x = fmaxf(mc.x, __shfl_xor(mc.x, off));
      mc.y = fmaxf(mc.y, __shfl_xor(mc.y, off));
      mc.z = fmaxf(mc.z, __shfl_xor(mc.z, off));
      mc.w = fmaxf(mc.w, __shfl_xor(mc.w, off));
    }
    float4 mn; mn.x = fmaxf(m4.x, mc.x); mn.y = fmaxf(m4.y, mc.y);
    mn.z = fmaxf(m4.z, mc.z); mn.w = fmaxf(m4.w, mc.w);
    float4 sc; sc.x = __expf(m4.x - mn.x); sc.y = __expf(m4.y - mn.y);
    sc.z = __expf(m4.z - mn.z); sc.w = __expf(m4.w - mn.w);
    m4 = mn;
    float4 p4 = make_float4(0,0,0,0);
    if (lane < C){
      p4.x = __expf(e4.x - mn.x); p4.y = __expf(e4.y - mn.y);
      p4.z = __expf(e4.z - mn.z); p4.w = __expf(e4.w - mn.w);
    }
    // wave sum per head
    float4 su = p4;
    #pragma unroll
    for (int off = 32; off; off >>= 1){
      su.x += __shfl_xor(su.x, off); su.y += __shfl_xor(su.y, off);
      su.z += __shfl_xor(su.z, off); su.w += __shfl_xor(su.w, off);
    }
    s4.x = s4.x*sc.x + su.x; s4.y = s4.y*sc.y + su.y;
    s4.z = s4.z*sc.z + su.z; s4.w = s4.w*sc.w + su.w;
    float asc = sel4(sc, h);
    acc.x *= asc; acc.y *= asc; acc.z *= asc; acc.w *= asc;
    // stage alpha-num + src in this wave's LDS slice (no barrier: same-wave order)
    *(float4*)&p_sh[w][lane*4] = p4;
    si_sh[w][lane] = si;
    // aggregate: one 1KB row per edge, 4 loads in flight via unroll
    #pragma unroll 4
    for (int j = 0; j < C; ++j){
      float a = p_sh[w][j*4 + h];
      int sj = si_sh[w][j];
      float4 f = *(const float4*)&feat[(size_t)sj*256 + lane*4];
      acc.x = fmaf(a, f.x, acc.x); acc.y = fmaf(a, f.y, acc.y);
      acc.z = fmaf(a, f.z, acc.z); acc.w = fmaf(a, f.w, acc.w);
    }
  }
  float4 o = make_float4(0,0,0,0);
  if (deg > 0){
    float rs = 1.0f / sel4(s4, h);
    o.x = acc.x * rs; o.y = acc.y * rs; o.z = acc.z * rs; o.w = acc.w * rs;
    o.x = o.x > 0.f ? o.x : expm1f(o.x);
    o.y = o.y > 0.f ? o.y : expm1f(o.y);
    o.z = o.z > 0.f ? o.z : expm1f(o.z);
    o.w = o.w > 0.f ? o.w : expm1f(o.w);
  }
  *(float4*)&h1[(size_t)n*256 + lane*4] = o;
}

// ---------------- fused softmax+aggregate, layer 2 (H=1, D=128): ONE WAVE PER NODE ----------------
// Aggregation: 2 edges per iteration (half-wave each, 512B x2 = 1KB per load pair).
__global__ __launch_bounds__(256) void k_fused2(
    const int* __restrict__ rowptr, const int* __restrict__ csr_src,
    const float* __restrict__ el, const float* __restrict__ er,
    const float* __restrict__ feat, float* __restrict__ out)
{
  __shared__ float p_sh[4][64];
  __shared__ int si_sh[4][64];
  int w = threadIdx.x >> 6, lane = threadIdx.x & 63;
  int n = blockIdx.x*4 + w;
  if (n >= NN) return;
  int b = rowptr[n], deg = rowptr[n+1] - b;
  float er_n = er[n];
  float m = -INFINITY, s = 0.f;
  float4 acc = make_float4(0,0,0,0);
  int half = lane >> 5, l32 = lane & 31;

  for (int c0 = 0; c0 < deg; c0 += 64){
    int C = min(64, deg - c0);
    int si = 0;
    float e = -INFINITY;
    if (lane < C){
      si = csr_src[b + c0 + lane];
      e = lrelu(el[si] + er_n);
    }
    float mc = e;
    #pragma unroll
    for (int off = 32; off; off >>= 1) mc = fmaxf(mc, __shfl_xor(mc, off));
    float mn = fmaxf(m, mc);
    float scl = __expf(m - mn);
    m = mn;
    float p = (lane < C) ? __expf(e - mn) : 0.f;
    float su = p;
    #pragma unroll
    for (int off = 32; off; off >>= 1) su += __shfl_xor(su, off);
    s = s*scl + su;
    acc.x *= scl; acc.y *= scl; acc.z *= scl; acc.w *= scl;
    p_sh[w][lane] = p;
    si_sh[w][lane] = si;
    int iters = (C + 1) >> 1;
    #pragma unroll 4
    for (int it = 0; it < iters; ++it){
      int e0 = 2*it + half;               // p_sh zero-padded -> e0 >= C contributes 0
      float a = p_sh[w][e0];
      int sj = si_sh[w][e0];
      float4 f = *(const float4*)&feat[(size_t)sj*128 + l32*4];
      acc.x = fmaf(a, f.x, acc.x); acc.y = fmaf(a, f.y, acc.y);
      acc.z = fmaf(a, f.z, acc.z); acc.w = fmaf(a, f.w, acc.w);
    }
  }
  // combine the two half-wave partials
  acc.x += __shfl_xor(acc.x, 32); acc.y += __shfl_xor(acc.y, 32);
  acc.z += __shfl_xor(acc.z, 32); acc.w += __shfl_xor(acc.w, 32);
  if (lane < 32){
    float4 o = make_float4(0,0,0,0);
    if (deg > 0){
      float rs = 1.0f / s;
      o.x = acc.x*rs; o.y = acc.y*rs; o.z = acc.z*rs; o.w = acc.w*rs;
    }
    *(float4*)&out[(size_t)n*128 + l32*4] = o;
  }
}

// ---------------- host launch ----------------
static inline size_t align256(size_t x){ return (x + 255) & ~(size_t)255; }

extern "C" void kernel_launch(void* const* d_in, const int* in_sizes, int n_in,
                              void* d_out, int out_size, void* d_ws, size_t ws_size,
                              hipStream_t stream){
  const float* h_in = (const float*)d_in[0];
  const int*   src  = (const int*)d_in[1];
  const int*   dst  = (const int*)d_in[2];
  const float* W1   = (const float*)d_in[3];
  const float* al1  = (const float*)d_in[4];
  const float* ar1  = (const float*)d_in[5];
  const float* W2   = (const float*)d_in[6];
  const float* al2  = (const float*)d_in[7];
  const float* ar2  = (const float*)d_in[8];
  float* out = (float*)d_out;

  char* ws = (char*)d_ws;
  size_t off = 0;
  float* feat1   = (float*)(ws + off); off = align256(off + (size_t)NN*256*4);  // reused as feat2
  float* h1      = (float*)(ws + off); off = align256(off + (size_t)NN*256*4);
  float* el1     = (float*)(ws + off); off = align256(off + (size_t)NN*4*4);
  float* er1     = (float*)(ws + off); off = align256(off + (size_t)NN*4*4);
  int* rowptr    = (int*)(ws + off);   off = align256(off + (size_t)(NN+1)*4);
  int* cnt       = (int*)(ws + off);   off = align256(off + (size_t)NN*4);
  int* csr_src   = (int*)(ws + off);   off = align256(off + (size_t)EE*4);
  if (off > ws_size) return;  // fail loudly: output stays poisoned

  float* feat2 = feat1;
  float* el2 = el1; float* er2 = er1;

  const int EB = (EE + 255)/256;
  const int FB = (NN + 3)/4;

  // CSR build
  hipMemsetAsync(cnt, 0, (size_t)NN*4, stream);
  k_hist<<<EB, 256, 0, stream>>>(dst, cnt, EE);
  k_scan<<<1, 1024, 0, stream>>>(cnt, rowptr, NN);
  hipMemsetAsync(cnt, 0, (size_t)NN*4, stream);
  k_scatter<<<EB, 256, 0, stream>>>(src, dst, rowptr, cnt, csr_src, EE);

  // ----- layer 1 -----
  k_sgemm<<<dim3(256/GBN, (NN+GBM-1)/GBM), 256, 0, stream>>>(h_in, W1, feat1, NN, 256, 256);
  k_elr1<<<NN, 256, 0, stream>>>(feat1, al1, ar1, el1, er1);
  k_fused1<<<FB, 256, 0, stream>>>(rowptr, csr_src, el1, er1, feat1, h1);

  // ----- layer 2 -----
  k_sgemm<<<dim3(128/GBN, (NN+GBM-1)/GBM), 256, 0, stream>>>(h1, W2, feat2, NN, 256, 128);
  k_elr2<<<NN, 64, 0, stream>>>(feat2, al2, ar2, el2, er2);
  k_fused2<<<FB, 256, 0, stream>>>(rowptr, csr_src, el2, er2, feat2, out);
}

// Round 4
// 393.411 us; speedup vs baseline: 2.2596x; 1.2347x over previous
//
#include <hip/hip_runtime.h>
#include <hip/hip_bf16.h>
#include <math.h>

#define NN 50000
#define EE 800000

__device__ __forceinline__ float lrelu(float v){ return v > 0.f ? v : 0.2f * v; }
__device__ __forceinline__ float sel4(float4 v, int h){
  return h == 0 ? v.x : h == 1 ? v.y : h == 2 ? v.z : v.w;
}
__device__ __forceinline__ ushort f2bf(float x){
  union { __hip_bfloat16 b; ushort u; } cv; cv.b = __float2bfloat16(x); return cv.u;
}
__device__ __forceinline__ float bf2f(ushort u){
  union { ushort u; __hip_bfloat16 b; } cv; cv.u = u; return __bfloat162float(cv.b);
}

typedef __attribute__((ext_vector_type(8))) short bf16x8;
typedef __attribute__((ext_vector_type(4))) float f32x4;

// ---------------- CSR build ----------------
__global__ void k_hist(const int* __restrict__ dst, int* __restrict__ cnt, int E){
  int i = blockIdx.x * blockDim.x + threadIdx.x;
  if (i < E) atomicAdd(&cnt[dst[i]], 1);
}

// parallel 3-phase scan over NN counts
__global__ __launch_bounds__(1024) void k_scan_bsum(const int* __restrict__ cnt, int* __restrict__ bsum, int n){
  __shared__ int ws[16];
  int t = threadIdx.x, i = blockIdx.x*1024 + t;
  int v = (i < n) ? cnt[i] : 0;
  #pragma unroll
  for (int off = 32; off; off >>= 1) v += __shfl_down(v, off);
  if ((t & 63) == 0) ws[t >> 6] = v;
  __syncthreads();
  if (t < 64){
    int x = (t < 16) ? ws[t] : 0;
    #pragma unroll
    for (int off = 32; off; off >>= 1) x += __shfl_down(x, off);
    if (t == 0) bsum[blockIdx.x] = x;
  }
}

__global__ void k_scan_boff(const int* __restrict__ bsum, int* __restrict__ boff,
                            int nb, int* __restrict__ rowptr, int n){
  int t = threadIdx.x;                   // one wave, nb <= 64
  int v = (t < nb) ? bsum[t] : 0;
  int x = v;
  #pragma unroll
  for (int off = 1; off < 64; off <<= 1){ int y = __shfl_up(x, off); if (t >= off) x += y; }
  if (t < nb) boff[t] = x - v;           // exclusive block offset
  if (t == 63) rowptr[n] = x;            // grand total
}

__global__ __launch_bounds__(1024) void k_scan_write(const int* __restrict__ cnt, const int* __restrict__ boff,
                                                     int* __restrict__ rowptr, int n){
  __shared__ int ws[16];
  int t = threadIdx.x, w = t >> 6, lane = t & 63, i = blockIdx.x*1024 + t;
  int v = (i < n) ? cnt[i] : 0;
  int x = v;
  #pragma unroll
  for (int off = 1; off < 64; off <<= 1){ int y = __shfl_up(x, off); if (lane >= off) x += y; }
  if (lane == 63) ws[w] = x;
  __syncthreads();
  if (t < 16){
    int y = ws[t];
    #pragma unroll
    for (int off = 1; off < 16; off <<= 1){ int z = __shfl_up(y, off); if (t >= off) y += z; }
    ws[t] = y;
  }
  __syncthreads();
  if (i < n) rowptr[i] = boff[blockIdx.x] + ((w > 0) ? ws[w-1] : 0) + x - v;
}

__global__ void k_scatter(const int* __restrict__ src, const int* __restrict__ dst,
                          const int* __restrict__ rowptr, int* __restrict__ cursor,
                          int* __restrict__ csr_src, int E){
  int i = blockIdx.x * blockDim.x + threadIdx.x;
  if (i < E){ int d = dst[i]; int p = rowptr[d] + atomicAdd(&cursor[d], 1); csr_src[p] = src[i]; }
}

// ---------------- W prep: fp32 [K][N] -> transposed split-bf16 [N][K] ----------------
__global__ void k_prepW(const float* __restrict__ W, ushort* __restrict__ Bth,
                        ushort* __restrict__ Btl, int K, int N){
  int k = blockIdx.x, n = threadIdx.x;
  float x = W[(size_t)k*N + n];
  ushort h = f2bf(x);
  ushort l = f2bf(x - bf2f(h));
  Bth[(size_t)n*K + k] = h;
  Btl[(size_t)n*K + k] = l;
}

// ---------------- split-bf16 MFMA GEMM: C[M,N] = A[M,K] @ B[K,N] ----------------
// A fp32 row-major (converted to bf16 hi/lo during LDS staging).
// B pre-transposed split-bf16 [N][K]. Tile 128x128, BK=32, 4 waves (2x2), each
// wave 64x64 via 4x4 tiles of mfma_f32_16x16x32_bf16, 3 products per tile.
#define LSTR 40   // LDS row stride in ushorts: 80B, 16B-aligned frags, <=4-way banks
__global__ __launch_bounds__(256) void k_mgemm(
    const float* __restrict__ A, const ushort* __restrict__ Bth, const ushort* __restrict__ Btl,
    float* __restrict__ C, int M, int K, int N)
{
  __shared__ __align__(16) ushort sAh[128*LSTR];
  __shared__ __align__(16) ushort sAl[128*LSTR];
  __shared__ __align__(16) ushort sBh[128*LSTR];
  __shared__ __align__(16) ushort sBl[128*LSTR];
  int tid = threadIdx.x;
  int bm = blockIdx.y*128, bn = blockIdx.x*128;
  int w = tid >> 6, lane = tid & 63;
  int wm = (w & 1)*64, wn = (w >> 1)*64;
  int fr = lane & 15, fg = lane >> 4;
  f32x4 acc[4][4] = {};

  for (int k0 = 0; k0 < K; k0 += 32){
    // stage A chunk (128 rows x 32 k) with fp32->bf16 hi/lo conversion
    #pragma unroll
    for (int r = 0; r < 4; ++r){
      int p = tid + 256*r;
      int row = p >> 3, kq = p & 7;
      int grow = bm + row;
      float4 av = (grow < M) ? *(const float4*)(A + (size_t)grow*K + k0 + kq*4)
                             : make_float4(0.f,0.f,0.f,0.f);
      ushort h0 = f2bf(av.x), h1 = f2bf(av.y), h2 = f2bf(av.z), h3 = f2bf(av.w);
      ushort l0 = f2bf(av.x - bf2f(h0)), l1 = f2bf(av.y - bf2f(h1));
      ushort l2 = f2bf(av.z - bf2f(h2)), l3 = f2bf(av.w - bf2f(h3));
      *(ushort4*)&sAh[row*LSTR + kq*4] = make_ushort4(h0, h1, h2, h3);
      *(ushort4*)&sAl[row*LSTR + kq*4] = make_ushort4(l0, l1, l2, l3);
    }
    // stage B chunk (128 n-rows x 32 k) straight copy
    #pragma unroll
    for (int r = 0; r < 2; ++r){
      int q = tid + 256*r;
      int row = q >> 2, part = q & 3;
      size_t g = (size_t)(bn + row)*K + k0 + part*8;
      *(uint4*)&sBh[row*LSTR + part*8] = *(const uint4*)(Bth + g);
      *(uint4*)&sBl[row*LSTR + part*8] = *(const uint4*)(Btl + g);
    }
    __syncthreads();
    bf16x8 ah[4], al[4], bh[4], bl[4];
    #pragma unroll
    for (int t4 = 0; t4 < 4; ++t4){
      int ai = (wm + t4*16 + fr)*LSTR + fg*8;
      ah[t4] = *(const bf16x8*)&sAh[ai];
      al[t4] = *(const bf16x8*)&sAl[ai];
      int bi = (wn + t4*16 + fr)*LSTR + fg*8;
      bh[t4] = *(const bf16x8*)&sBh[bi];
      bl[t4] = *(const bf16x8*)&sBl[bi];
    }
    #pragma unroll
    for (int ti = 0; ti < 4; ++ti)
      #pragma unroll
      for (int tj = 0; tj < 4; ++tj){
        acc[ti][tj] = __builtin_amdgcn_mfma_f32_16x16x32_bf16(ah[ti], bh[tj], acc[ti][tj], 0,0,0);
        acc[ti][tj] = __builtin_amdgcn_mfma_f32_16x16x32_bf16(ah[ti], bl[tj], acc[ti][tj], 0,0,0);
        acc[ti][tj] = __builtin_amdgcn_mfma_f32_16x16x32_bf16(al[ti], bh[tj], acc[ti][tj], 0,0,0);
      }
    __syncthreads();
  }
  // epilogue: C[row][col], row = 4*fg + i within tile, col = fr
  #pragma unroll
  for (int ti = 0; ti < 4; ++ti)
    #pragma unroll
    for (int i = 0; i < 4; ++i){
      int row = bm + wm + ti*16 + fg*4 + i;
      if (row < M){
        #pragma unroll
        for (int tj = 0; tj < 4; ++tj)
          C[(size_t)row*N + bn + wn + tj*16 + fr] = acc[ti][tj][i];
      }
    }
}

// ---------------- el/er projections ----------------
__global__ void k_elr1(const float* __restrict__ feat, const float* __restrict__ al,
                       const float* __restrict__ ar, float* __restrict__ el, float* __restrict__ er){
  int n = blockIdx.x, t = threadIdx.x;
  float x = feat[(size_t)n*256 + t];
  float pl = x * al[t], pr = x * ar[t];
  #pragma unroll
  for (int off = 32; off; off >>= 1){ pl += __shfl_down(pl, off); pr += __shfl_down(pr, off); }
  if ((t & 63) == 0){ int h = t >> 6; el[n*4 + h] = pl; er[n*4 + h] = pr; }
}

__global__ void k_elr2(const float* __restrict__ feat, const float* __restrict__ al,
                       const float* __restrict__ ar, float* __restrict__ el, float* __restrict__ er){
  int n = blockIdx.x, t = threadIdx.x;
  float x0 = feat[(size_t)n*128 + t], x1 = feat[(size_t)n*128 + 64 + t];
  float pl = x0*al[t] + x1*al[64+t];
  float pr = x0*ar[t] + x1*ar[64+t];
  #pragma unroll
  for (int off = 32; off; off >>= 1){ pl += __shfl_down(pl, off); pr += __shfl_down(pr, off); }
  if (t == 0){ el[n] = pl; er[n] = pr; }
}

// ---------------- fused softmax+aggregate, layer 1: ONE WAVE PER NODE ----------------
__global__ __launch_bounds__(256) void k_fused1(
    const int* __restrict__ rowptr, const int* __restrict__ csr_src,
    const float* __restrict__ el, const float* __restrict__ er,
    const float* __restrict__ feat, float* __restrict__ h1)
{
  __shared__ __align__(16) float p_sh[4][64*4];
  __shared__ int si_sh[4][64];
  int w = threadIdx.x >> 6, lane = threadIdx.x & 63;
  int n = blockIdx.x*4 + w;
  if (n >= NN) return;
  int b = rowptr[n], deg = rowptr[n+1] - b;
  int h = lane >> 4;
  float4 er4 = *(const float4*)&er[n*4];
  float4 m4 = make_float4(-INFINITY,-INFINITY,-INFINITY,-INFINITY);
  float4 s4 = make_float4(0,0,0,0);
  float4 acc = make_float4(0,0,0,0);

  for (int c0 = 0; c0 < deg; c0 += 64){
    int C = min(64, deg - c0);
    int si = 0;
    float4 e4 = make_float4(-INFINITY,-INFINITY,-INFINITY,-INFINITY);
    if (lane < C){
      si = csr_src[b + c0 + lane];
      float4 l4 = *(const float4*)&el[si*4];
      e4.x = lrelu(l4.x + er4.x); e4.y = lrelu(l4.y + er4.y);
      e4.z = lrelu(l4.z + er4.z); e4.w = lrelu(l4.w + er4.w);
    }
    float4 mc = e4;
    #pragma unroll
    for (int off = 32; off; off >>= 1){
      mc.x = fmaxf(mc.x, __shfl_xor(mc.x, off));
      mc.y = fmaxf(mc.y, __shfl_xor(mc.y, off));
      mc.z = fmaxf(mc.z, __shfl_xor(mc.z, off));
      mc.w = fmaxf(mc.w, __shfl_xor(mc.w, off));
    }
    float4 mn; mn.x = fmaxf(m4.x, mc.x); mn.y = fmaxf(m4.y, mc.y);
    mn.z = fmaxf(m4.z, mc.z); mn.w = fmaxf(m4.w, mc.w);
    float4 sc; sc.x = __expf(m4.x - mn.x); sc.y = __expf(m4.y - mn.y);
    sc.z = __expf(m4.z - mn.z); sc.w = __expf(m4.w - mn.w);
    m4 = mn;
    float4 p4 = make_float4(0,0,0,0);
    if (lane < C){
      p4.x = __expf(e4.x - mn.x); p4.y = __expf(e4.y - mn.y);
      p4.z = __expf(e4.z - mn.z); p4.w = __expf(e4.w - mn.w);
    }
    float4 su = p4;
    #pragma unroll
    for (int off = 32; off; off >>= 1){
      su.x += __shfl_xor(su.x, off); su.y += __shfl_xor(su.y, off);
      su.z += __shfl_xor(su.z, off); su.w += __shfl_xor(su.w, off);
    }
    s4.x = s4.x*sc.x + su.x; s4.y = s4.y*sc.y + su.y;
    s4.z = s4.z*sc.z + su.z; s4.w = s4.w*sc.w + su.w;
    float asc = sel4(sc, h);
    acc.x *= asc; acc.y *= asc; acc.z *= asc; acc.w *= asc;
    *(float4*)&p_sh[w][lane*4] = p4;
    si_sh[w][lane] = si;
    #pragma unroll 4
    for (int j = 0; j < C; ++j){
      float a = p_sh[w][j*4 + h];
      int sj = si_sh[w][j];
      float4 f = *(const float4*)&feat[(size_t)sj*256 + lane*4];
      acc.x = fmaf(a, f.x, acc.x); acc.y = fmaf(a, f.y, acc.y);
      acc.z = fmaf(a, f.z, acc.z); acc.w = fmaf(a, f.w, acc.w);
    }
  }
  float4 o = make_float4(0,0,0,0);
  if (deg > 0){
    float rs = 1.0f / sel4(s4, h);
    o.x = acc.x * rs; o.y = acc.y * rs; o.z = acc.z * rs; o.w = acc.w * rs;
    o.x = o.x > 0.f ? o.x : expm1f(o.x);
    o.y = o.y > 0.f ? o.y : expm1f(o.y);
    o.z = o.z > 0.f ? o.z : expm1f(o.z);
    o.w = o.w > 0.f ? o.w : expm1f(o.w);
  }
  *(float4*)&h1[(size_t)n*256 + lane*4] = o;
}

// ---------------- fused softmax+aggregate, layer 2 (H=1, D=128) ----------------
__global__ __launch_bounds__(256) void k_fused2(
    const int* __restrict__ rowptr, const int* __restrict__ csr_src,
    const float* __restrict__ el, const float* __restrict__ er,
    const float* __restrict__ feat, float* __restrict__ out)
{
  __shared__ float p_sh[4][64];
  __shared__ int si_sh[4][64];
  int w = threadIdx.x >> 6, lane = threadIdx.x & 63;
  int n = blockIdx.x*4 + w;
  if (n >= NN) return;
  int b = rowptr[n], deg = rowptr[n+1] - b;
  float er_n = er[n];
  float m = -INFINITY, s = 0.f;
  float4 acc = make_float4(0,0,0,0);
  int half = lane >> 5, l32 = lane & 31;

  for (int c0 = 0; c0 < deg; c0 += 64){
    int C = min(64, deg - c0);
    int si = 0;
    float e = -INFINITY;
    if (lane < C){
      si = csr_src[b + c0 + lane];
      e = lrelu(el[si] + er_n);
    }
    float mc = e;
    #pragma unroll
    for (int off = 32; off; off >>= 1) mc = fmaxf(mc, __shfl_xor(mc, off));
    float mn = fmaxf(m, mc);
    float scl = __expf(m - mn);
    m = mn;
    float p = (lane < C) ? __expf(e - mn) : 0.f;
    float su = p;
    #pragma unroll
    for (int off = 32; off; off >>= 1) su += __shfl_xor(su, off);
    s = s*scl + su;
    acc.x *= scl; acc.y *= scl; acc.z *= scl; acc.w *= scl;
    p_sh[w][lane] = p;
    si_sh[w][lane] = si;
    int iters = (C + 1) >> 1;
    #pragma unroll 4
    for (int it = 0; it < iters; ++it){
      int e0 = 2*it + half;
      float a = p_sh[w][e0];
      int sj = si_sh[w][e0];
      float4 f = *(const float4*)&feat[(size_t)sj*128 + l32*4];
      acc.x = fmaf(a, f.x, acc.x); acc.y = fmaf(a, f.y, acc.y);
      acc.z = fmaf(a, f.z, acc.z); acc.w = fmaf(a, f.w, acc.w);
    }
  }
  acc.x += __shfl_xor(acc.x, 32); acc.y += __shfl_xor(acc.y, 32);
  acc.z += __shfl_xor(acc.z, 32); acc.w += __shfl_xor(acc.w, 32);
  if (lane < 32){
    float4 o = make_float4(0,0,0,0);
    if (deg > 0){
      float rs = 1.0f / s;
      o.x = acc.x*rs; o.y = acc.y*rs; o.z = acc.z*rs; o.w = acc.w*rs;
    }
    *(float4*)&out[(size_t)n*128 + l32*4] = o;
  }
}

// ---------------- host launch ----------------
static inline size_t align256(size_t x){ return (x + 255) & ~(size_t)255; }

extern "C" void kernel_launch(void* const* d_in, const int* in_sizes, int n_in,
                              void* d_out, int out_size, void* d_ws, size_t ws_size,
                              hipStream_t stream){
  const float* h_in = (const float*)d_in[0];
  const int*   src  = (const int*)d_in[1];
  const int*   dst  = (const int*)d_in[2];
  const float* W1   = (const float*)d_in[3];
  const float* al1  = (const float*)d_in[4];
  const float* ar1  = (const float*)d_in[5];
  const float* W2   = (const float*)d_in[6];
  const float* al2  = (const float*)d_in[7];
  const float* ar2  = (const float*)d_in[8];
  float* out = (float*)d_out;

  char* ws = (char*)d_ws;
  size_t off = 0;
  float* feat1   = (float*)(ws + off); off = align256(off + (size_t)NN*256*4);  // reused as feat2
  float* h1      = (float*)(ws + off); off = align256(off + (size_t)NN*256*4);
  float* el1     = (float*)(ws + off); off = align256(off + (size_t)NN*4*4);
  float* er1     = (float*)(ws + off); off = align256(off + (size_t)NN*4*4);
  int* rowptr    = (int*)(ws + off);   off = align256(off + (size_t)(NN+1)*4);
  int* cnt       = (int*)(ws + off);   off = align256(off + (size_t)NN*4);
  int* csr_src   = (int*)(ws + off);   off = align256(off + (size_t)EE*4);
  ushort* Bth1   = (ushort*)(ws + off); off = align256(off + (size_t)256*256*2);
  ushort* Btl1   = (ushort*)(ws + off); off = align256(off + (size_t)256*256*2);
  ushort* Bth2   = (ushort*)(ws + off); off = align256(off + (size_t)128*256*2);
  ushort* Btl2   = (ushort*)(ws + off); off = align256(off + (size_t)128*256*2);
  int* bsum      = (int*)(ws + off);   off = align256(off + (size_t)64*4);
  int* boff      = (int*)(ws + off);   off = align256(off + (size_t)64*4);
  if (off > ws_size) return;  // fail loudly: output stays poisoned

  float* feat2 = feat1;
  float* el2 = el1; float* er2 = er1;

  const int EB = (EE + 255)/256;
  const int FB = (NN + 3)/4;
  const int NB = (NN + 1023)/1024;           // 49 scan blocks
  const int MT = (NN + 127)/128;             // 391 M-tiles

  // CSR build
  hipMemsetAsync(cnt, 0, (size_t)NN*4, stream);
  k_hist<<<EB, 256, 0, stream>>>(dst, cnt, EE);
  k_scan_bsum<<<NB, 1024, 0, stream>>>(cnt, bsum, NN);
  k_scan_boff<<<1, 64, 0, stream>>>(bsum, boff, NB, rowptr, NN);
  k_scan_write<<<NB, 1024, 0, stream>>>(cnt, boff, rowptr, NN);
  hipMemsetAsync(cnt, 0, (size_t)NN*4, stream);
  k_scatter<<<EB, 256, 0, stream>>>(src, dst, rowptr, cnt, csr_src, EE);

  // weight prep (tiny)
  k_prepW<<<256, 256, 0, stream>>>(W1, Bth1, Btl1, 256, 256);
  k_prepW<<<256, 128, 0, stream>>>(W2, Bth2, Btl2, 256, 128);

  // ----- layer 1 -----
  k_mgemm<<<dim3(2, MT), 256, 0, stream>>>(h_in, Bth1, Btl1, feat1, NN, 256, 256);
  k_elr1<<<NN, 256, 0, stream>>>(feat1, al1, ar1, el1, er1);
  k_fused1<<<FB, 256, 0, stream>>>(rowptr, csr_src, el1, er1, feat1, h1);

  // ----- layer 2 -----
  k_mgemm<<<dim3(1, MT), 256, 0, stream>>>(h1, Bth2, Btl2, feat2, NN, 256, 128);
  k_elr2<<<NN, 64, 0, stream>>>(feat2, al2, ar2, el2, er2);
  k_fused2<<<FB, 256, 0, stream>>>(rowptr, csr_src, el2, er2, feat2, out);
}

// Round 5
// 326.686 us; speedup vs baseline: 2.7211x; 1.2042x over previous
//
#include <hip/hip_runtime.h>
#include <hip/hip_bf16.h>
#include <math.h>

#define NN 50000
#define EE 800000

__device__ __forceinline__ float lrelu(float v){ return v > 0.f ? v : 0.2f * v; }
__device__ __forceinline__ float sel4(float4 v, int h){
  return h == 0 ? v.x : h == 1 ? v.y : h == 2 ? v.z : v.w;
}
__device__ __forceinline__ ushort f2bf(float x){
  union { __hip_bfloat16 b; ushort u; } cv; cv.b = __float2bfloat16(x); return cv.u;
}
__device__ __forceinline__ float bf2f(ushort u){
  union { uint u; float f; } cv; cv.u = (uint)u << 16; return cv.f;
}

typedef __attribute__((ext_vector_type(8))) short bf16x8;
typedef __attribute__((ext_vector_type(4))) float f32x4;

// ---------------- CSR build ----------------
__global__ void k_hist(const int* __restrict__ dst, int* __restrict__ cnt, int E){
  int i = blockIdx.x * blockDim.x + threadIdx.x;
  if (i < E) atomicAdd(&cnt[dst[i]], 1);
}

__global__ __launch_bounds__(1024) void k_scan_bsum(const int* __restrict__ cnt, int* __restrict__ bsum, int n){
  __shared__ int ws[16];
  int t = threadIdx.x, i = blockIdx.x*1024 + t;
  int v = (i < n) ? cnt[i] : 0;
  #pragma unroll
  for (int off = 32; off; off >>= 1) v += __shfl_down(v, off);
  if ((t & 63) == 0) ws[t >> 6] = v;
  __syncthreads();
  if (t < 64){
    int x = (t < 16) ? ws[t] : 0;
    #pragma unroll
    for (int off = 32; off; off >>= 1) x += __shfl_down(x, off);
    if (t == 0) bsum[blockIdx.x] = x;
  }
}

__global__ void k_scan_boff(const int* __restrict__ bsum, int* __restrict__ boff,
                            int nb, int* __restrict__ rowptr, int n){
  int t = threadIdx.x;
  int v = (t < nb) ? bsum[t] : 0;
  int x = v;
  #pragma unroll
  for (int off = 1; off < 64; off <<= 1){ int y = __shfl_up(x, off); if (t >= off) x += y; }
  if (t < nb) boff[t] = x - v;
  if (t == 63) rowptr[n] = x;
}

__global__ __launch_bounds__(1024) void k_scan_write(const int* __restrict__ cnt, const int* __restrict__ boff,
                                                     int* __restrict__ rowptr, int n){
  __shared__ int ws[16];
  int t = threadIdx.x, w = t >> 6, lane = t & 63, i = blockIdx.x*1024 + t;
  int v = (i < n) ? cnt[i] : 0;
  int x = v;
  #pragma unroll
  for (int off = 1; off < 64; off <<= 1){ int y = __shfl_up(x, off); if (lane >= off) x += y; }
  if (lane == 63) ws[w] = x;
  __syncthreads();
  if (t < 16){
    int y = ws[t];
    #pragma unroll
    for (int off = 1; off < 16; off <<= 1){ int z = __shfl_up(y, off); if (t >= off) y += z; }
    ws[t] = y;
  }
  __syncthreads();
  if (i < n) rowptr[i] = boff[blockIdx.x] + ((w > 0) ? ws[w-1] : 0) + x - v;
}

__global__ void k_scatter(const int* __restrict__ src, const int* __restrict__ dst,
                          int* __restrict__ cursor, int* __restrict__ csr_src, int E){
  int i = blockIdx.x * blockDim.x + threadIdx.x;
  if (i < E){ int p = atomicAdd(&cursor[dst[i]], 1); csr_src[p] = src[i]; }
}

// ---------------- W prep: fp32 [K][N] -> transposed split-bf16 [N][K] ----------------
__global__ void k_prepW(const float* __restrict__ W, ushort* __restrict__ Bth,
                        ushort* __restrict__ Btl, int K, int N){
  int k = blockIdx.x, n = threadIdx.x;
  float x = W[(size_t)k*N + n];
  ushort h = f2bf(x);
  ushort l = f2bf(x - bf2f(h));
  Bth[(size_t)n*K + k] = h;
  Btl[(size_t)n*K + k] = l;
}

// ---------------- split-bf16 MFMA GEMM + fused el/er epilogue ----------------
// MODE 1: C out = bf16 (featb), N=256, 4 heads of 64 cols; each (row,head) owned by
//         exactly one wave -> direct el/er store.
// MODE 2: C out = fp32 (feat2), N=128, 1 head; two waves per row -> atomicAdd el/er.
#define LSTR 40
template<int MODE>
__global__ __launch_bounds__(256) void k_mgemm(
    const float* __restrict__ A, const ushort* __restrict__ Bth, const ushort* __restrict__ Btl,
    void* __restrict__ Cout, const float* __restrict__ avl, const float* __restrict__ avr,
    float* __restrict__ el, float* __restrict__ er, int M, int K, int N)
{
  __shared__ __align__(16) ushort sAh[128*LSTR];
  __shared__ __align__(16) ushort sAl[128*LSTR];
  __shared__ __align__(16) ushort sBh[128*LSTR];
  __shared__ __align__(16) ushort sBl[128*LSTR];
  int tid = threadIdx.x;
  int bm = blockIdx.y*128, bn = blockIdx.x*128;
  int w = tid >> 6, lane = tid & 63;
  int wm = (w & 1)*64, wn = (w >> 1)*64;
  int fr = lane & 15, fg = lane >> 4;
  f32x4 acc[4][4] = {};

  for (int k0 = 0; k0 < K; k0 += 32){
    #pragma unroll
    for (int r = 0; r < 4; ++r){
      int p = tid + 256*r;
      int row = p >> 3, kq = p & 7;
      int grow = bm + row;
      float4 av = (grow < M) ? *(const float4*)(A + (size_t)grow*K + k0 + kq*4)
                             : make_float4(0.f,0.f,0.f,0.f);
      ushort h0 = f2bf(av.x), h1 = f2bf(av.y), h2 = f2bf(av.z), h3 = f2bf(av.w);
      ushort l0 = f2bf(av.x - bf2f(h0)), l1 = f2bf(av.y - bf2f(h1));
      ushort l2 = f2bf(av.z - bf2f(h2)), l3 = f2bf(av.w - bf2f(h3));
      *(ushort4*)&sAh[row*LSTR + kq*4] = make_ushort4(h0, h1, h2, h3);
      *(ushort4*)&sAl[row*LSTR + kq*4] = make_ushort4(l0, l1, l2, l3);
    }
    #pragma unroll
    for (int r = 0; r < 2; ++r){
      int q = tid + 256*r;
      int row = q >> 2, part = q & 3;
      size_t g = (size_t)(bn + row)*K + k0 + part*8;
      *(uint4*)&sBh[row*LSTR + part*8] = *(const uint4*)(Bth + g);
      *(uint4*)&sBl[row*LSTR + part*8] = *(const uint4*)(Btl + g);
    }
    __syncthreads();
    bf16x8 ah[4], al_[4], bh[4], bl[4];
    #pragma unroll
    for (int t4 = 0; t4 < 4; ++t4){
      int ai = (wm + t4*16 + fr)*LSTR + fg*8;
      ah[t4] = *(const bf16x8*)&sAh[ai];
      al_[t4] = *(const bf16x8*)&sAl[ai];
      int bi = (wn + t4*16 + fr)*LSTR + fg*8;
      bh[t4] = *(const bf16x8*)&sBh[bi];
      bl[t4] = *(const bf16x8*)&sBl[bi];
    }
    #pragma unroll
    for (int ti = 0; ti < 4; ++ti)
      #pragma unroll
      for (int tj = 0; tj < 4; ++tj){
        acc[ti][tj] = __builtin_amdgcn_mfma_f32_16x16x32_bf16(ah[ti], bh[tj], acc[ti][tj], 0,0,0);
        acc[ti][tj] = __builtin_amdgcn_mfma_f32_16x16x32_bf16(ah[ti], bl[tj], acc[ti][tj], 0,0,0);
        acc[ti][tj] = __builtin_amdgcn_mfma_f32_16x16x32_bf16(al_[ti], bh[tj], acc[ti][tj], 0,0,0);
      }
    __syncthreads();
  }
  // per-lane attention weights for this wave's 64-col slice
  int colbase = bn + wn;
  int hH = colbase >> 6;                 // head (MODE 1); 0 for MODE 2
  float wl[4], wr[4];
  #pragma unroll
  for (int tj = 0; tj < 4; ++tj){
    int c = (MODE == 1) ? (hH*64 + tj*16 + fr) : (colbase + tj*16 + fr);
    wl[tj] = avl[c]; wr[tj] = avr[c];
  }
  #pragma unroll
  for (int ti = 0; ti < 4; ++ti)
    #pragma unroll
    for (int i = 0; i < 4; ++i){
      int row = bm + wm + ti*16 + fg*4 + i;
      if (row < M){
        float pl = 0.f, pr = 0.f;
        #pragma unroll
        for (int tj = 0; tj < 4; ++tj){
          float v = acc[ti][tj][i];
          pl = fmaf(v, wl[tj], pl);
          pr = fmaf(v, wr[tj], pr);
          int col = colbase + tj*16 + fr;
          if (MODE == 1) ((ushort*)Cout)[(size_t)row*256 + col] = f2bf(v);
          else           ((float*)Cout)[(size_t)row*128 + col] = v;
        }
        #pragma unroll
        for (int mk = 1; mk < 16; mk <<= 1){
          pl += __shfl_xor(pl, mk);
          pr += __shfl_xor(pr, mk);
        }
        if (fr == 0){
          if (MODE == 1){ el[row*4 + hH] = pl; er[row*4 + hH] = pr; }
          else { atomicAdd(&el[row], pl); atomicAdd(&er[row], pr); }
        }
      }
    }
}

// ---------------- fused softmax+aggregate, layer 1 (bf16 gather) ----------------
__global__ __launch_bounds__(256) void k_fused1(
    const int* __restrict__ rowptr, const int* __restrict__ csr_src,
    const float* __restrict__ el, const float* __restrict__ er,
    const ushort* __restrict__ featb, float* __restrict__ h1)
{
  __shared__ __align__(16) float p_sh[4][64*4];
  __shared__ int si_sh[4][64];
  int w = threadIdx.x >> 6, lane = threadIdx.x & 63;
  int n = blockIdx.x*4 + w;
  if (n >= NN) return;
  int b = rowptr[n], deg = rowptr[n+1] - b;
  int h = lane >> 4;
  float4 er4 = *(const float4*)&er[n*4];
  float4 m4 = make_float4(-INFINITY,-INFINITY,-INFINITY,-INFINITY);
  float4 s4 = make_float4(0,0,0,0);
  float4 acc = make_float4(0,0,0,0);

  for (int c0 = 0; c0 < deg; c0 += 64){
    int C = min(64, deg - c0);
    int si = 0;
    float4 e4 = make_float4(-INFINITY,-INFINITY,-INFINITY,-INFINITY);
    if (lane < C){
      si = csr_src[b + c0 + lane];
      float4 l4 = *(const float4*)&el[si*4];
      e4.x = lrelu(l4.x + er4.x); e4.y = lrelu(l4.y + er4.y);
      e4.z = lrelu(l4.z + er4.z); e4.w = lrelu(l4.w + er4.w);
    }
    float4 mc = e4;
    #pragma unroll
    for (int off = 32; off; off >>= 1){
      mc.x = fmaxf(mc.x, __shfl_xor(mc.x, off));
      mc.y = fmaxf(mc.y, __shfl_xor(mc.y, off));
      mc.z = fmaxf(mc.z, __shfl_xor(mc.z, off));
      mc.w = fmaxf(mc.w, __shfl_xor(mc.w, off));
    }
    float4 mn; mn.x = fmaxf(m4.x, mc.x); mn.y = fmaxf(m4.y, mc.y);
    mn.z = fmaxf(m4.z, mc.z); mn.w = fmaxf(m4.w, mc.w);
    float4 sc; sc.x = __expf(m4.x - mn.x); sc.y = __expf(m4.y - mn.y);
    sc.z = __expf(m4.z - mn.z); sc.w = __expf(m4.w - mn.w);
    m4 = mn;
    float4 p4 = make_float4(0,0,0,0);
    if (lane < C){
      p4.x = __expf(e4.x - mn.x); p4.y = __expf(e4.y - mn.y);
      p4.z = __expf(e4.z - mn.z); p4.w = __expf(e4.w - mn.w);
    }
    float4 su = p4;
    #pragma unroll
    for (int off = 32; off; off >>= 1){
      su.x += __shfl_xor(su.x, off); su.y += __shfl_xor(su.y, off);
      su.z += __shfl_xor(su.z, off); su.w += __shfl_xor(su.w, off);
    }
    s4.x = s4.x*sc.x + su.x; s4.y = s4.y*sc.y + su.y;
    s4.z = s4.z*sc.z + su.z; s4.w = s4.w*sc.w + su.w;
    float asc = sel4(sc, h);
    acc.x *= asc; acc.y *= asc; acc.z *= asc; acc.w *= asc;
    *(float4*)&p_sh[w][lane*4] = p4;
    si_sh[w][lane] = si;
    #pragma unroll 4
    for (int j = 0; j < C; ++j){
      float a = p_sh[w][j*4 + h];
      int sj = si_sh[w][j];
      ushort4 u = *(const ushort4*)&featb[(size_t)sj*256 + lane*4];
      acc.x = fmaf(a, bf2f(u.x), acc.x); acc.y = fmaf(a, bf2f(u.y), acc.y);
      acc.z = fmaf(a, bf2f(u.z), acc.z); acc.w = fmaf(a, bf2f(u.w), acc.w);
    }
  }
  float4 o = make_float4(0,0,0,0);
  if (deg > 0){
    float rs = 1.0f / sel4(s4, h);
    o.x = acc.x * rs; o.y = acc.y * rs; o.z = acc.z * rs; o.w = acc.w * rs;
    o.x = o.x > 0.f ? o.x : expm1f(o.x);
    o.y = o.y > 0.f ? o.y : expm1f(o.y);
    o.z = o.z > 0.f ? o.z : expm1f(o.z);
    o.w = o.w > 0.f ? o.w : expm1f(o.w);
  }
  *(float4*)&h1[(size_t)n*256 + lane*4] = o;
}

// ---------------- fused softmax+aggregate, layer 2 (fp32 gather) ----------------
__global__ __launch_bounds__(256) void k_fused2(
    const int* __restrict__ rowptr, const int* __restrict__ csr_src,
    const float* __restrict__ el, const float* __restrict__ er,
    const float* __restrict__ feat, float* __restrict__ out)
{
  __shared__ float p_sh[4][64];
  __shared__ int si_sh[4][64];
  int w = threadIdx.x >> 6, lane = threadIdx.x & 63;
  int n = blockIdx.x*4 + w;
  if (n >= NN) return;
  int b = rowptr[n], deg = rowptr[n+1] - b;
  float er_n = er[n];
  float m = -INFINITY, s = 0.f;
  float4 acc = make_float4(0,0,0,0);
  int half = lane >> 5, l32 = lane & 31;

  for (int c0 = 0; c0 < deg; c0 += 64){
    int C = min(64, deg - c0);
    int si = 0;
    float e = -INFINITY;
    if (lane < C){
      si = csr_src[b + c0 + lane];
      e = lrelu(el[si] + er_n);
    }
    float mc = e;
    #pragma unroll
    for (int off = 32; off; off >>= 1) mc = fmaxf(mc, __shfl_xor(mc, off));
    float mn = fmaxf(m, mc);
    float scl = __expf(m - mn);
    m = mn;
    float p = (lane < C) ? __expf(e - mn) : 0.f;
    float su = p;
    #pragma unroll
    for (int off = 32; off; off >>= 1) su += __shfl_xor(su, off);
    s = s*scl + su;
    acc.x *= scl; acc.y *= scl; acc.z *= scl; acc.w *= scl;
    p_sh[w][lane] = p;
    si_sh[w][lane] = si;
    int iters = (C + 1) >> 1;
    #pragma unroll 4
    for (int it = 0; it < iters; ++it){
      int e0 = 2*it + half;
      float a = p_sh[w][e0];
      int sj = si_sh[w][e0];
      float4 f = *(const float4*)&feat[(size_t)sj*128 + l32*4];
      acc.x = fmaf(a, f.x, acc.x); acc.y = fmaf(a, f.y, acc.y);
      acc.z = fmaf(a, f.z, acc.z); acc.w = fmaf(a, f.w, acc.w);
    }
  }
  acc.x += __shfl_xor(acc.x, 32); acc.y += __shfl_xor(acc.y, 32);
  acc.z += __shfl_xor(acc.z, 32); acc.w += __shfl_xor(acc.w, 32);
  if (lane < 32){
    float4 o = make_float4(0,0,0,0);
    if (deg > 0){
      float rs = 1.0f / s;
      o.x = acc.x*rs; o.y = acc.y*rs; o.z = acc.z*rs; o.w = acc.w*rs;
    }
    *(float4*)&out[(size_t)n*128 + l32*4] = o;
  }
}

// ---------------- host launch ----------------
static inline size_t align256(size_t x){ return (x + 255) & ~(size_t)255; }

extern "C" void kernel_launch(void* const* d_in, const int* in_sizes, int n_in,
                              void* d_out, int out_size, void* d_ws, size_t ws_size,
                              hipStream_t stream){
  const float* h_in = (const float*)d_in[0];
  const int*   src  = (const int*)d_in[1];
  const int*   dst  = (const int*)d_in[2];
  const float* W1   = (const float*)d_in[3];
  const float* al1  = (const float*)d_in[4];
  const float* ar1  = (const float*)d_in[5];
  const float* W2   = (const float*)d_in[6];
  const float* al2  = (const float*)d_in[7];
  const float* ar2  = (const float*)d_in[8];
  float* out = (float*)d_out;

  char* ws = (char*)d_ws;
  size_t off = 0;
  ushort* featb  = (ushort*)(ws + off); off = align256(off + (size_t)NN*256*2);  // bf16 layer1 features
  float* h1      = (float*)(ws + off);  off = align256(off + (size_t)NN*256*4);
  float* feat2   = (float*)(ws + off);  off = align256(off + (size_t)NN*128*4);
  float* el1     = (float*)(ws + off);  off = align256(off + (size_t)NN*4*4);
  float* er1     = (float*)(ws + off);  off = align256(off + (size_t)NN*4*4);
  int* rowptr    = (int*)(ws + off);    off = align256(off + (size_t)(NN+1)*4);
  int* cnt       = (int*)(ws + off);    off = align256(off + (size_t)NN*4);
  int* cursor    = (int*)(ws + off);    off = align256(off + (size_t)NN*4);
  int* csr_src   = (int*)(ws + off);    off = align256(off + (size_t)EE*4);
  ushort* Bth1   = (ushort*)(ws + off); off = align256(off + (size_t)256*256*2);
  ushort* Btl1   = (ushort*)(ws + off); off = align256(off + (size_t)256*256*2);
  ushort* Bth2   = (ushort*)(ws + off); off = align256(off + (size_t)128*256*2);
  ushort* Btl2   = (ushort*)(ws + off); off = align256(off + (size_t)128*256*2);
  int* bsum      = (int*)(ws + off);    off = align256(off + (size_t)64*4);
  int* boff      = (int*)(ws + off);    off = align256(off + (size_t)64*4);
  if (off > ws_size) return;  // fail loudly: output stays poisoned

  float* el2 = el1;   // reuse as float[NN]
  float* er2 = er1;

  const int EB = (EE + 255)/256;
  const int FB = (NN + 3)/4;
  const int NB = (NN + 1023)/1024;
  const int MT = (NN + 127)/128;

  // CSR build
  hipMemsetAsync(cnt, 0, (size_t)NN*4, stream);
  k_hist<<<EB, 256, 0, stream>>>(dst, cnt, EE);
  k_scan_bsum<<<NB, 1024, 0, stream>>>(cnt, bsum, NN);
  k_scan_boff<<<1, 64, 0, stream>>>(bsum, boff, NB, rowptr, NN);
  k_scan_write<<<NB, 1024, 0, stream>>>(cnt, boff, rowptr, NN);
  hipMemcpyAsync(cursor, rowptr, (size_t)NN*4, hipMemcpyDeviceToDevice, stream);
  k_scatter<<<EB, 256, 0, stream>>>(src, dst, cursor, csr_src, EE);

  // weight prep (tiny)
  k_prepW<<<256, 256, 0, stream>>>(W1, Bth1, Btl1, 256, 256);
  k_prepW<<<256, 128, 0, stream>>>(W2, Bth2, Btl2, 256, 128);

  // ----- layer 1 -----
  k_mgemm<1><<<dim3(2, MT), 256, 0, stream>>>(h_in, Bth1, Btl1, featb, al1, ar1, el1, er1, NN, 256, 256);
  k_fused1<<<FB, 256, 0, stream>>>(rowptr, csr_src, el1, er1, featb, h1);

  // ----- layer 2 -----
  hipMemsetAsync(el2, 0, (size_t)NN*4, stream);
  hipMemsetAsync(er2, 0, (size_t)NN*4, stream);
  k_mgemm<2><<<dim3(1, MT), 256, 0, stream>>>(h1, Bth2, Btl2, feat2, al2, ar2, el2, er2, NN, 256, 128);
  k_fused2<<<FB, 256, 0, stream>>>(rowptr, csr_src, el2, er2, feat2, out);
}

// Round 6
// 312.095 us; speedup vs baseline: 2.8483x; 1.0468x over previous
//
#include <hip/hip_runtime.h>
#include <hip/hip_bf16.h>
#include <math.h>

#define NN 50000
#define EE 800000

__device__ __forceinline__ float lrelu(float v){ return v > 0.f ? v : 0.2f * v; }
__device__ __forceinline__ float sel4(float4 v, int h){
  return h == 0 ? v.x : h == 1 ? v.y : h == 2 ? v.z : v.w;
}
__device__ __forceinline__ ushort f2bf(float x){
  union { __hip_bfloat16 b; ushort u; } cv; cv.b = __float2bfloat16(x); return cv.u;
}
__device__ __forceinline__ float bf2f(ushort u){
  union { uint u; float f; } cv; cv.u = (uint)u << 16; return cv.f;
}

typedef __attribute__((ext_vector_type(8))) short bf16x8;
typedef __attribute__((ext_vector_type(4))) float f32x4;

// async global->LDS, 16B per lane (CK-style address-space dance)
__device__ __forceinline__ void gload16(const ushort* g, ushort* l){
  const auto* gp = reinterpret_cast<const __attribute__((address_space(1))) ushort*>((size_t)g);
  auto* lp = reinterpret_cast<__attribute__((address_space(3))) ushort*>((size_t)l);
  __builtin_amdgcn_global_load_lds(gp, lp, 16, 0, 0);
}

// ---------------- CSR build ----------------
__global__ void k_hist(const int* __restrict__ dst, int* __restrict__ cnt, int E){
  int i = blockIdx.x * blockDim.x + threadIdx.x;
  if (i < E) atomicAdd(&cnt[dst[i]], 1);
}

__global__ __launch_bounds__(1024) void k_scan_bsum(const int* __restrict__ cnt, int* __restrict__ bsum, int n){
  __shared__ int ws[16];
  int t = threadIdx.x, i = blockIdx.x*1024 + t;
  int v = (i < n) ? cnt[i] : 0;
  #pragma unroll
  for (int off = 32; off; off >>= 1) v += __shfl_down(v, off);
  if ((t & 63) == 0) ws[t >> 6] = v;
  __syncthreads();
  if (t < 64){
    int x = (t < 16) ? ws[t] : 0;
    #pragma unroll
    for (int off = 32; off; off >>= 1) x += __shfl_down(x, off);
    if (t == 0) bsum[blockIdx.x] = x;
  }
}

__global__ void k_scan_boff(const int* __restrict__ bsum, int* __restrict__ boff,
                            int nb, int* __restrict__ rowptr, int n){
  int t = threadIdx.x;
  int v = (t < nb) ? bsum[t] : 0;
  int x = v;
  #pragma unroll
  for (int off = 1; off < 64; off <<= 1){ int y = __shfl_up(x, off); if (t >= off) x += y; }
  if (t < nb) boff[t] = x - v;
  if (t == 63) rowptr[n] = x;
}

__global__ __launch_bounds__(1024) void k_scan_write(const int* __restrict__ cnt, const int* __restrict__ boff,
                                                     int* __restrict__ rowptr, int n){
  __shared__ int ws[16];
  int t = threadIdx.x, w = t >> 6, lane = t & 63, i = blockIdx.x*1024 + t;
  int v = (i < n) ? cnt[i] : 0;
  int x = v;
  #pragma unroll
  for (int off = 1; off < 64; off <<= 1){ int y = __shfl_up(x, off); if (lane >= off) x += y; }
  if (lane == 63) ws[w] = x;
  __syncthreads();
  if (t < 16){
    int y = ws[t];
    #pragma unroll
    for (int off = 1; off < 16; off <<= 1){ int z = __shfl_up(y, off); if (t >= off) y += z; }
    ws[t] = y;
  }
  __syncthreads();
  if (i < n) rowptr[i] = boff[blockIdx.x] + ((w > 0) ? ws[w-1] : 0) + x - v;
}

__global__ void k_scatter(const int* __restrict__ src, const int* __restrict__ dst,
                          int* __restrict__ cursor, int* __restrict__ csr_src, int E){
  int i = blockIdx.x * blockDim.x + threadIdx.x;
  if (i < E){ int p = atomicAdd(&cursor[dst[i]], 1); csr_src[p] = src[i]; }
}

// ---------------- W prep: fp32 [K][N] -> transposed split-bf16 [N][K] ----------------
__global__ void k_prepW(const float* __restrict__ W, ushort* __restrict__ Bth,
                        ushort* __restrict__ Btl, int K, int N){
  int k = blockIdx.x, n = threadIdx.x;
  float x = W[(size_t)k*N + n];
  ushort h = f2bf(x);
  ushort l = f2bf(x - bf2f(h));
  Bth[(size_t)n*K + k] = h;
  Btl[(size_t)n*K + k] = l;
}

// ---------------- A prep: fp32 row-major -> split-bf16 hi/lo (same layout) ----------------
__global__ void k_prepA(const float* __restrict__ A, ushort* __restrict__ Ah,
                        ushort* __restrict__ Al, int total4){
  int i = blockIdx.x*blockDim.x + threadIdx.x;
  if (i >= total4) return;
  float4 v = ((const float4*)A)[i];
  ushort h0 = f2bf(v.x), h1 = f2bf(v.y), h2 = f2bf(v.z), h3 = f2bf(v.w);
  ushort l0 = f2bf(v.x - bf2f(h0)), l1 = f2bf(v.y - bf2f(h1));
  ushort l2 = f2bf(v.z - bf2f(h2)), l3 = f2bf(v.w - bf2f(h3));
  ((ushort4*)Ah)[i] = make_ushort4(h0, h1, h2, h3);
  ((ushort4*)Al)[i] = make_ushort4(l0, l1, l2, l3);
}

// ---------------- split-bf16 MFMA GEMM + fused el/er epilogue ----------------
// A pre-split bf16 [M][K] hi/lo; B pre-split bf16 [N][K] hi/lo. Tile 128x128, BK=32,
// 8 waves (4M x 2N), wave = 32x64 via 2x4 mfma_f32_16x16x32_bf16 tiles, 3 products.
// Staging via global_load_lds (16B/lane), linear LDS, per-wave 1KB slices.
// MODE 1: Cout = bf16 featb (N=256, head = col/64, one wave per (row,head) -> direct el/er).
// MODE 2: Cout = fp32 feat2 (N=128, 2 waves/row -> atomicAdd el/er; 2 adds = deterministic).
template<int MODE>
__global__ __launch_bounds__(512, 4) void k_mgemm(
    const ushort* __restrict__ Ah, const ushort* __restrict__ Al,
    const ushort* __restrict__ Bth, const ushort* __restrict__ Btl,
    void* __restrict__ Cout, const float* __restrict__ avl, const float* __restrict__ avr,
    float* __restrict__ el, float* __restrict__ er, int M, int K, int N)
{
  __shared__ __align__(16) ushort sAh[128*32];
  __shared__ __align__(16) ushort sAl[128*32];
  __shared__ __align__(16) ushort sBh[128*32];
  __shared__ __align__(16) ushort sBl[128*32];
  int tid = threadIdx.x;
  int w = tid >> 6, lane = tid & 63;
  int bm = blockIdx.y*128, bn = blockIdx.x*128;
  int wm = (w & 3)*32, wn = (w >> 2)*64;
  int fr = lane & 15, fg = lane >> 4;

  // staging: wave w owns rows 16w..16w+15 of the 128-row tile; lane -> (row, 16B k-seg)
  int srow = 16*w + (lane >> 2);
  int skoff = (lane & 3)*8;
  int arow = bm + srow; if (arow > M-1) arow = M-1;       // clamp OOB (epilogue guards)
  const ushort* gAh = Ah + (size_t)arow*K + skoff;
  const ushort* gAl = Al + (size_t)arow*K + skoff;
  const ushort* gBh = Bth + (size_t)(bn + srow)*K + skoff;
  const ushort* gBl = Btl + (size_t)(bn + srow)*K + skoff;
  ushort* lAh = &sAh[16*w*32];
  ushort* lAl = &sAl[16*w*32];
  ushort* lBh = &sBh[16*w*32];
  ushort* lBl = &sBl[16*w*32];

  f32x4 acc[2][4] = {};
  for (int k0 = 0; k0 < K; k0 += 32){
    gload16(gAh + k0, lAh);
    gload16(gAl + k0, lAl);
    gload16(gBh + k0, lBh);
    gload16(gBl + k0, lBl);
    __syncthreads();
    bf16x8 ah[2], alo[2], bh[4], blo[4];
    #pragma unroll
    for (int ti = 0; ti < 2; ++ti){
      int ai = (wm + ti*16 + fr)*32 + fg*8;
      ah[ti]  = *(const bf16x8*)&sAh[ai];
      alo[ti] = *(const bf16x8*)&sAl[ai];
    }
    #pragma unroll
    for (int tj = 0; tj < 4; ++tj){
      int bi = (wn + tj*16 + fr)*32 + fg*8;
      bh[tj]  = *(const bf16x8*)&sBh[bi];
      blo[tj] = *(const bf16x8*)&sBl[bi];
    }
    #pragma unroll
    for (int ti = 0; ti < 2; ++ti)
      #pragma unroll
      for (int tj = 0; tj < 4; ++tj){
        acc[ti][tj] = __builtin_amdgcn_mfma_f32_16x16x32_bf16(ah[ti], bh[tj], acc[ti][tj], 0,0,0);
        acc[ti][tj] = __builtin_amdgcn_mfma_f32_16x16x32_bf16(ah[ti], blo[tj], acc[ti][tj], 0,0,0);
        acc[ti][tj] = __builtin_amdgcn_mfma_f32_16x16x32_bf16(alo[ti], bh[tj], acc[ti][tj], 0,0,0);
      }
    __syncthreads();
  }

  int colhead = bn + wn;                 // multiple of 64
  float wl[4], wr[4];
  #pragma unroll
  for (int tj = 0; tj < 4; ++tj){
    int c = colhead + tj*16 + fr;
    wl[tj] = avl[c]; wr[tj] = avr[c];
  }
  #pragma unroll
  for (int ti = 0; ti < 2; ++ti)
    #pragma unroll
    for (int i = 0; i < 4; ++i){
      int row = bm + wm + ti*16 + fg*4 + i;
      if (row < M){
        float pl = 0.f, pr = 0.f;
        #pragma unroll
        for (int tj = 0; tj < 4; ++tj){
          float v = acc[ti][tj][i];
          pl = fmaf(v, wl[tj], pl);
          pr = fmaf(v, wr[tj], pr);
          int col = colhead + tj*16 + fr;
          if (MODE == 1) ((ushort*)Cout)[(size_t)row*256 + col] = f2bf(v);
          else           ((float*)Cout)[(size_t)row*128 + col] = v;
        }
        #pragma unroll
        for (int mk = 1; mk < 16; mk <<= 1){
          pl += __shfl_xor(pl, mk);
          pr += __shfl_xor(pr, mk);
        }
        if (fr == 0){
          if (MODE == 1){ el[row*4 + (colhead >> 6)] = pl; er[row*4 + (colhead >> 6)] = pr; }
          else { atomicAdd(&el[row], pl); atomicAdd(&er[row], pr); }
        }
      }
    }
}

// ---------------- fused softmax+aggregate, layer 1 (bf16 gather, split-bf16 h1 out) ----------------
__global__ __launch_bounds__(256) void k_fused1(
    const int* __restrict__ rowptr, const int* __restrict__ csr_src,
    const float* __restrict__ el, const float* __restrict__ er,
    const ushort* __restrict__ featb, ushort* __restrict__ h1h, ushort* __restrict__ h1l)
{
  __shared__ __align__(16) float p_sh[4][64*4];
  __shared__ int si_sh[4][64];
  int w = threadIdx.x >> 6, lane = threadIdx.x & 63;
  int n = blockIdx.x*4 + w;
  if (n >= NN) return;
  int b = rowptr[n], deg = rowptr[n+1] - b;
  int h = lane >> 4;
  float4 er4 = *(const float4*)&er[n*4];
  float4 m4 = make_float4(-INFINITY,-INFINITY,-INFINITY,-INFINITY);
  float4 s4 = make_float4(0,0,0,0);
  float4 acc = make_float4(0,0,0,0);

  for (int c0 = 0; c0 < deg; c0 += 64){
    int C = min(64, deg - c0);
    int si = 0;
    float4 e4 = make_float4(-INFINITY,-INFINITY,-INFINITY,-INFINITY);
    if (lane < C){
      si = csr_src[b + c0 + lane];
      float4 l4 = *(const float4*)&el[si*4];
      e4.x = lrelu(l4.x + er4.x); e4.y = lrelu(l4.y + er4.y);
      e4.z = lrelu(l4.z + er4.z); e4.w = lrelu(l4.w + er4.w);
    }
    float4 mc = e4;
    #pragma unroll
    for (int off = 32; off; off >>= 1){
      mc.x = fmaxf(mc.x, __shfl_xor(mc.x, off));
      mc.y = fmaxf(mc.y, __shfl_xor(mc.y, off));
      mc.z = fmaxf(mc.z, __shfl_xor(mc.z, off));
      mc.w = fmaxf(mc.w, __shfl_xor(mc.w, off));
    }
    float4 mn; mn.x = fmaxf(m4.x, mc.x); mn.y = fmaxf(m4.y, mc.y);
    mn.z = fmaxf(m4.z, mc.z); mn.w = fmaxf(m4.w, mc.w);
    float4 sc; sc.x = __expf(m4.x - mn.x); sc.y = __expf(m4.y - mn.y);
    sc.z = __expf(m4.z - mn.z); sc.w = __expf(m4.w - mn.w);
    m4 = mn;
    float4 p4 = make_float4(0,0,0,0);
    if (lane < C){
      p4.x = __expf(e4.x - mn.x); p4.y = __expf(e4.y - mn.y);
      p4.z = __expf(e4.z - mn.z); p4.w = __expf(e4.w - mn.w);
    }
    float4 su = p4;
    #pragma unroll
    for (int off = 32; off; off >>= 1){
      su.x += __shfl_xor(su.x, off); su.y += __shfl_xor(su.y, off);
      su.z += __shfl_xor(su.z, off); su.w += __shfl_xor(su.w, off);
    }
    s4.x = s4.x*sc.x + su.x; s4.y = s4.y*sc.y + su.y;
    s4.z = s4.z*sc.z + su.z; s4.w = s4.w*sc.w + su.w;
    float asc = sel4(sc, h);
    acc.x *= asc; acc.y *= asc; acc.z *= asc; acc.w *= asc;
    *(float4*)&p_sh[w][lane*4] = p4;
    si_sh[w][lane] = si;
    #pragma unroll 4
    for (int j = 0; j < C; ++j){
      float a = p_sh[w][j*4 + h];
      int sj = si_sh[w][j];
      ushort4 u = *(const ushort4*)&featb[(size_t)sj*256 + lane*4];
      acc.x = fmaf(a, bf2f(u.x), acc.x); acc.y = fmaf(a, bf2f(u.y), acc.y);
      acc.z = fmaf(a, bf2f(u.z), acc.z); acc.w = fmaf(a, bf2f(u.w), acc.w);
    }
  }
  float4 o = make_float4(0,0,0,0);
  if (deg > 0){
    float rs = 1.0f / sel4(s4, h);
    o.x = acc.x * rs; o.y = acc.y * rs; o.z = acc.z * rs; o.w = acc.w * rs;
    o.x = o.x > 0.f ? o.x : expm1f(o.x);
    o.y = o.y > 0.f ? o.y : expm1f(o.y);
    o.z = o.z > 0.f ? o.z : expm1f(o.z);
    o.w = o.w > 0.f ? o.w : expm1f(o.w);
  }
  ushort4 oh, ol;
  oh.x = f2bf(o.x); ol.x = f2bf(o.x - bf2f(oh.x));
  oh.y = f2bf(o.y); ol.y = f2bf(o.y - bf2f(oh.y));
  oh.z = f2bf(o.z); ol.z = f2bf(o.z - bf2f(oh.z));
  oh.w = f2bf(o.w); ol.w = f2bf(o.w - bf2f(oh.w));
  *(ushort4*)&h1h[(size_t)n*256 + lane*4] = oh;
  *(ushort4*)&h1l[(size_t)n*256 + lane*4] = ol;
}

// ---------------- fused softmax+aggregate, layer 2 (fp32 gather) ----------------
__global__ __launch_bounds__(256) void k_fused2(
    const int* __restrict__ rowptr, const int* __restrict__ csr_src,
    const float* __restrict__ el, const float* __restrict__ er,
    const float* __restrict__ feat, float* __restrict__ out)
{
  __shared__ float p_sh[4][64];
  __shared__ int si_sh[4][64];
  int w = threadIdx.x >> 6, lane = threadIdx.x & 63;
  int n = blockIdx.x*4 + w;
  if (n >= NN) return;
  int b = rowptr[n], deg = rowptr[n+1] - b;
  float er_n = er[n];
  float m = -INFINITY, s = 0.f;
  float4 acc = make_float4(0,0,0,0);
  int half = lane >> 5, l32 = lane & 31;

  for (int c0 = 0; c0 < deg; c0 += 64){
    int C = min(64, deg - c0);
    int si = 0;
    float e = -INFINITY;
    if (lane < C){
      si = csr_src[b + c0 + lane];
      e = lrelu(el[si] + er_n);
    }
    float mc = e;
    #pragma unroll
    for (int off = 32; off; off >>= 1) mc = fmaxf(mc, __shfl_xor(mc, off));
    float mn = fmaxf(m, mc);
    float scl = __expf(m - mn);
    m = mn;
    float p = (lane < C) ? __expf(e - mn) : 0.f;
    float su = p;
    #pragma unroll
    for (int off = 32; off; off >>= 1) su += __shfl_xor(su, off);
    s = s*scl + su;
    acc.x *= scl; acc.y *= scl; acc.z *= scl; acc.w *= scl;
    p_sh[w][lane] = p;
    si_sh[w][lane] = si;
    int iters = (C + 1) >> 1;
    #pragma unroll 4
    for (int it = 0; it < iters; ++it){
      int e0 = 2*it + half;
      float a = p_sh[w][e0];
      int sj = si_sh[w][e0];
      float4 f = *(const float4*)&feat[(size_t)sj*128 + l32*4];
      acc.x = fmaf(a, f.x, acc.x); acc.y = fmaf(a, f.y, acc.y);
      acc.z = fmaf(a, f.z, acc.z); acc.w = fmaf(a, f.w, acc.w);
    }
  }
  acc.x += __shfl_xor(acc.x, 32); acc.y += __shfl_xor(acc.y, 32);
  acc.z += __shfl_xor(acc.z, 32); acc.w += __shfl_xor(acc.w, 32);
  if (lane < 32){
    float4 o = make_float4(0,0,0,0);
    if (deg > 0){
      float rs = 1.0f / s;
      o.x = acc.x*rs; o.y = acc.y*rs; o.z = acc.z*rs; o.w = acc.w*rs;
    }
    *(float4*)&out[(size_t)n*128 + l32*4] = o;
  }
}

// ---------------- host launch ----------------
static inline size_t align256(size_t x){ return (x + 255) & ~(size_t)255; }

extern "C" void kernel_launch(void* const* d_in, const int* in_sizes, int n_in,
                              void* d_out, int out_size, void* d_ws, size_t ws_size,
                              hipStream_t stream){
  const float* h_in = (const float*)d_in[0];
  const int*   src  = (const int*)d_in[1];
  const int*   dst  = (const int*)d_in[2];
  const float* W1   = (const float*)d_in[3];
  const float* al1  = (const float*)d_in[4];
  const float* ar1  = (const float*)d_in[5];
  const float* W2   = (const float*)d_in[6];
  const float* al2  = (const float*)d_in[7];
  const float* ar2  = (const float*)d_in[8];
  float* out = (float*)d_out;

  char* ws = (char*)d_ws;
  size_t off = 0;
  ushort* Ah     = (ushort*)(ws + off); off = align256(off + (size_t)NN*256*2);  // reused as h1h
  ushort* Al     = (ushort*)(ws + off); off = align256(off + (size_t)NN*256*2);  // reused as h1l
  ushort* featb  = (ushort*)(ws + off); off = align256(off + (size_t)NN*256*2);
  float* feat2   = (float*)(ws + off);  off = align256(off + (size_t)NN*128*4);
  float* el1     = (float*)(ws + off);  off = align256(off + (size_t)NN*4*4);
  float* er1     = (float*)(ws + off);  off = align256(off + (size_t)NN*4*4);
  int* rowptr    = (int*)(ws + off);    off = align256(off + (size_t)(NN+1)*4);
  int* cnt       = (int*)(ws + off);    off = align256(off + (size_t)NN*4);
  int* cursor    = (int*)(ws + off);    off = align256(off + (size_t)NN*4);
  int* csr_src   = (int*)(ws + off);    off = align256(off + (size_t)EE*4);
  ushort* Bth1   = (ushort*)(ws + off); off = align256(off + (size_t)256*256*2);
  ushort* Btl1   = (ushort*)(ws + off); off = align256(off + (size_t)256*256*2);
  ushort* Bth2   = (ushort*)(ws + off); off = align256(off + (size_t)128*256*2);
  ushort* Btl2   = (ushort*)(ws + off); off = align256(off + (size_t)128*256*2);
  int* bsum      = (int*)(ws + off);    off = align256(off + (size_t)64*4);
  int* boff      = (int*)(ws + off);    off = align256(off + (size_t)64*4);
  if (off > ws_size) return;  // fail loudly: output stays poisoned

  ushort* h1h = Ah;   // safe alias: A-split dead after GEMM1
  ushort* h1l = Al;
  float* el2 = el1;   // reuse as float[NN]
  float* er2 = er1;

  const int EB = (EE + 255)/256;
  const int FB = (NN + 3)/4;
  const int NB = (NN + 1023)/1024;
  const int MT = (NN + 127)/128;

  // CSR build
  hipMemsetAsync(cnt, 0, (size_t)NN*4, stream);
  k_hist<<<EB, 256, 0, stream>>>(dst, cnt, EE);
  k_scan_bsum<<<NB, 1024, 0, stream>>>(cnt, bsum, NN);
  k_scan_boff<<<1, 64, 0, stream>>>(bsum, boff, NB, rowptr, NN);
  k_scan_write<<<NB, 1024, 0, stream>>>(cnt, boff, rowptr, NN);
  hipMemcpyAsync(cursor, rowptr, (size_t)NN*4, hipMemcpyDeviceToDevice, stream);
  k_scatter<<<EB, 256, 0, stream>>>(src, dst, cursor, csr_src, EE);

  // prep (tiny + one 51MB pass)
  k_prepW<<<256, 256, 0, stream>>>(W1, Bth1, Btl1, 256, 256);
  k_prepW<<<256, 128, 0, stream>>>(W2, Bth2, Btl2, 256, 128);
  k_prepA<<<(NN*64 + 255)/256, 256, 0, stream>>>(h_in, Ah, Al, NN*64);

  // ----- layer 1 -----
  k_mgemm<1><<<dim3(2, MT), 512, 0, stream>>>(Ah, Al, Bth1, Btl1, featb, al1, ar1, el1, er1, NN, 256, 256);
  k_fused1<<<FB, 256, 0, stream>>>(rowptr, csr_src, el1, er1, featb, h1h, h1l);

  // ----- layer 2 -----
  hipMemsetAsync(el2, 0, (size_t)NN*4, stream);
  hipMemsetAsync(er2, 0, (size_t)NN*4, stream);
  k_mgemm<2><<<dim3(1, MT), 512, 0, stream>>>(h1h, h1l, Bth2, Btl2, feat2, al2, ar2, el2, er2, NN, 256, 128);
  k_fused2<<<FB, 256, 0, stream>>>(rowptr, csr_src, el2, er2, feat2, out);
}

// Round 7
// 286.199 us; speedup vs baseline: 3.1060x; 1.0905x over previous
//
#include <hip/hip_runtime.h>
#include <hip/hip_bf16.h>
#include <math.h>

#define NN 50000
#define EE 800000

__device__ __forceinline__ float lrelu(float v){ return v > 0.f ? v : 0.2f * v; }
__device__ __forceinline__ float sel4(float4 v, int h){
  return h == 0 ? v.x : h == 1 ? v.y : h == 2 ? v.z : v.w;
}
__device__ __forceinline__ ushort f2bf(float x){
  union { __hip_bfloat16 b; ushort u; } cv; cv.b = __float2bfloat16(x); return cv.u;
}
__device__ __forceinline__ float bf2f(ushort u){
  union { uint u; float f; } cv; cv.u = (uint)u << 16; return cv.f;
}

typedef __attribute__((ext_vector_type(8))) short bf16x8;
typedef __attribute__((ext_vector_type(4))) float f32x4;

// async global->LDS, 16B per lane
__device__ __forceinline__ void gload16(const ushort* g, ushort* l){
  const auto* gp = reinterpret_cast<const __attribute__((address_space(1))) ushort*>((size_t)g);
  auto* lp = reinterpret_cast<__attribute__((address_space(3))) ushort*>((size_t)l);
  __builtin_amdgcn_global_load_lds(gp, lp, 16, 0, 0);
}

// ---------------- CSR build ----------------
__global__ void k_hist(const int* __restrict__ dst, int* __restrict__ cnt, int E){
  int i = blockIdx.x * blockDim.x + threadIdx.x;
  if (i < E) atomicAdd(&cnt[dst[i]], 1);
}

__global__ __launch_bounds__(1024) void k_scan_bsum(const int* __restrict__ cnt, int* __restrict__ bsum, int n){
  __shared__ int ws[16];
  int t = threadIdx.x, i = blockIdx.x*1024 + t;
  int v = (i < n) ? cnt[i] : 0;
  #pragma unroll
  for (int off = 32; off; off >>= 1) v += __shfl_down(v, off);
  if ((t & 63) == 0) ws[t >> 6] = v;
  __syncthreads();
  if (t < 64){
    int x = (t < 16) ? ws[t] : 0;
    #pragma unroll
    for (int off = 32; off; off >>= 1) x += __shfl_down(x, off);
    if (t == 0) bsum[blockIdx.x] = x;
  }
}

__global__ void k_scan_boff(const int* __restrict__ bsum, int* __restrict__ boff,
                            int nb, int* __restrict__ rowptr, int n){
  int t = threadIdx.x;
  int v = (t < nb) ? bsum[t] : 0;
  int x = v;
  #pragma unroll
  for (int off = 1; off < 64; off <<= 1){ int y = __shfl_up(x, off); if (t >= off) x += y; }
  if (t < nb) boff[t] = x - v;
  if (t == 63) rowptr[n] = x;
}

__global__ __launch_bounds__(1024) void k_scan_write(const int* __restrict__ cnt, const int* __restrict__ boff,
                                                     int* __restrict__ rowptr, int n){
  __shared__ int ws[16];
  int t = threadIdx.x, w = t >> 6, lane = t & 63, i = blockIdx.x*1024 + t;
  int v = (i < n) ? cnt[i] : 0;
  int x = v;
  #pragma unroll
  for (int off = 1; off < 64; off <<= 1){ int y = __shfl_up(x, off); if (lane >= off) x += y; }
  if (lane == 63) ws[w] = x;
  __syncthreads();
  if (t < 16){
    int y = ws[t];
    #pragma unroll
    for (int off = 1; off < 16; off <<= 1){ int z = __shfl_up(y, off); if (t >= off) y += z; }
    ws[t] = y;
  }
  __syncthreads();
  if (i < n) rowptr[i] = boff[blockIdx.x] + ((w > 0) ? ws[w-1] : 0) + x - v;
}

__global__ void k_scatter(const int* __restrict__ src, const int* __restrict__ dst,
                          int* __restrict__ cursor, int* __restrict__ csr_src, int E){
  int i = blockIdx.x * blockDim.x + threadIdx.x;
  if (i < E){ int p = atomicAdd(&cursor[dst[i]], 1); csr_src[p] = src[i]; }
}

// ---------------- W prep: fp32 [K][N] -> transposed split-bf16 [N][K] ----------------
__global__ void k_prepW(const float* __restrict__ W, ushort* __restrict__ Bth,
                        ushort* __restrict__ Btl, int K, int N){
  int k = blockIdx.x, n = threadIdx.x;
  float x = W[(size_t)k*N + n];
  ushort h = f2bf(x);
  ushort l = f2bf(x - bf2f(h));
  Bth[(size_t)n*K + k] = h;
  Btl[(size_t)n*K + k] = l;
}

// ---------------- A prep: fp32 row-major -> bf16 (hi only) ----------------
__global__ void k_prepA(const float* __restrict__ A, ushort* __restrict__ Ab, int total4){
  int i = blockIdx.x*blockDim.x + threadIdx.x;
  if (i >= total4) return;
  float4 v = ((const float4*)A)[i];
  ((ushort4*)Ab)[i] = make_ushort4(f2bf(v.x), f2bf(v.y), f2bf(v.z), f2bf(v.w));
}

// ---------------- bf16-A x split-bf16-B MFMA GEMM + fused el/er epilogue ----------------
// A bf16 [M][K]; B split bf16 [N][K] hi/lo. Tile 128x128, BK=32, 8 waves (4M x 2N),
// wave = 32x64 via 2x4 mfma_f32_16x16x32_bf16 tiles, 2 products (ah*bh + ah*bl).
// Double-buffered global_load_lds staging: STAGE(next) issued before ds_read+MFMA.
// MODE 1: Cout = bf16 featb (N=256, head = col/64, one wave per (row,head) -> direct el/er).
// MODE 2: Cout = fp32 feat2 (N=128); 2 waves/row combine el/er partials via LDS.
template<int MODE>
__global__ __launch_bounds__(512, 4) void k_mgemm(
    const ushort* __restrict__ Ab,
    const ushort* __restrict__ Bth, const ushort* __restrict__ Btl,
    void* __restrict__ Cout, const float* __restrict__ avl, const float* __restrict__ avr,
    float* __restrict__ el, float* __restrict__ er, int M, int K, int N)
{
  __shared__ __align__(16) ushort sA[2][128*32];
  __shared__ __align__(16) ushort sBh[2][128*32];
  __shared__ __align__(16) ushort sBl[2][128*32];
  __shared__ float sEL[2][128], sER[2][128];   // MODE 2 combine
  int tid = threadIdx.x;
  int w = tid >> 6, lane = tid & 63;
  int bm = blockIdx.y*128, bn = blockIdx.x*128;
  int wm = (w & 3)*32, wn = (w >> 2)*64;
  int fr = lane & 15, fg = lane >> 4;

  // staging: wave w owns rows 16w..16w+15; lane -> (row, 16B k-seg); linear LDS
  int srow = 16*w + (lane >> 2);
  int skoff = (lane & 3)*8;
  int arow = bm + srow; if (arow > M-1) arow = M-1;       // clamp OOB (epilogue guards)
  const ushort* gA  = Ab  + (size_t)arow*K + skoff;
  const ushort* gBh = Bth + (size_t)(bn + srow)*K + skoff;
  const ushort* gBl = Btl + (size_t)(bn + srow)*K + skoff;
  int lslice = 16*w*32;

  const int nk = K >> 5;
  // prologue: stage tile 0
  gload16(gA,  &sA[0][lslice]);
  gload16(gBh, &sBh[0][lslice]);
  gload16(gBl, &sBl[0][lslice]);
  __syncthreads();

  f32x4 acc[2][4] = {};
  for (int kt = 0; kt < nk; ++kt){
    int buf = kt & 1;
    if (kt + 1 < nk){
      int k1 = (kt + 1) << 5;
      gload16(gA + k1,  &sA[buf^1][lslice]);
      gload16(gBh + k1, &sBh[buf^1][lslice]);
      gload16(gBl + k1, &sBl[buf^1][lslice]);
    }
    bf16x8 ah[2], bh[4], bl[4];
    #pragma unroll
    for (int ti = 0; ti < 2; ++ti)
      ah[ti] = *(const bf16x8*)&sA[buf][(wm + ti*16 + fr)*32 + fg*8];
    #pragma unroll
    for (int tj = 0; tj < 4; ++tj){
      int bi = (wn + tj*16 + fr)*32 + fg*8;
      bh[tj] = *(const bf16x8*)&sBh[buf][bi];
      bl[tj] = *(const bf16x8*)&sBl[buf][bi];
    }
    #pragma unroll
    for (int ti = 0; ti < 2; ++ti)
      #pragma unroll
      for (int tj = 0; tj < 4; ++tj){
        acc[ti][tj] = __builtin_amdgcn_mfma_f32_16x16x32_bf16(ah[ti], bh[tj], acc[ti][tj], 0,0,0);
        acc[ti][tj] = __builtin_amdgcn_mfma_f32_16x16x32_bf16(ah[ti], bl[tj], acc[ti][tj], 0,0,0);
      }
    __syncthreads();   // drains staging vmcnt + protects buf swap
  }

  int colhead = bn + wn;                 // multiple of 64
  float wl[4], wr[4];
  #pragma unroll
  for (int tj = 0; tj < 4; ++tj){
    int c = colhead + tj*16 + fr;
    wl[tj] = avl[c]; wr[tj] = avr[c];
  }
  #pragma unroll
  for (int ti = 0; ti < 2; ++ti)
    #pragma unroll
    for (int i = 0; i < 4; ++i){
      int row = bm + wm + ti*16 + fg*4 + i;
      float pl = 0.f, pr = 0.f;
      #pragma unroll
      for (int tj = 0; tj < 4; ++tj){
        float v = acc[ti][tj][i];
        pl = fmaf(v, wl[tj], pl);
        pr = fmaf(v, wr[tj], pr);
        if (row < M){
          int col = colhead + tj*16 + fr;
          if (MODE == 1) ((ushort*)Cout)[(size_t)row*256 + col] = f2bf(v);
          else           ((float*)Cout)[(size_t)row*128 + col] = v;
        }
      }
      #pragma unroll
      for (int mk = 1; mk < 16; mk <<= 1){
        pl += __shfl_xor(pl, mk);
        pr += __shfl_xor(pr, mk);
      }
      if (fr == 0){
        if (MODE == 1){
          if (row < M){ el[row*4 + (colhead >> 6)] = pl; er[row*4 + (colhead >> 6)] = pr; }
        } else {
          int lr = wm + ti*16 + fg*4 + i;       // 0..127 within tile
          sEL[w >> 2][lr] = pl; sER[w >> 2][lr] = pr;
        }
      }
    }
  if (MODE == 2){
    __syncthreads();
    if (tid < 128){
      int row = bm + tid;
      if (row < M){
        el[row] = sEL[0][tid] + sEL[1][tid];
        er[row] = sER[0][tid] + sER[1][tid];
      }
    }
  }
}

// ---------------- fused softmax+aggregate, layer 1 (bf16 gather, bf16 h1 out) ----------------
__global__ __launch_bounds__(256) void k_fused1(
    const int* __restrict__ rowptr, const int* __restrict__ csr_src,
    const float* __restrict__ el, const float* __restrict__ er,
    const ushort* __restrict__ featb, ushort* __restrict__ h1b)
{
  __shared__ __align__(16) float p_sh[4][64*4];
  __shared__ int si_sh[4][64];
  int w = threadIdx.x >> 6, lane = threadIdx.x & 63;
  int n = blockIdx.x*4 + w;
  if (n >= NN) return;
  int b = rowptr[n], deg = rowptr[n+1] - b;
  int h = lane >> 4;
  float4 er4 = *(const float4*)&er[n*4];
  float4 m4 = make_float4(-INFINITY,-INFINITY,-INFINITY,-INFINITY);
  float4 s4 = make_float4(0,0,0,0);
  float4 acc = make_float4(0,0,0,0);

  for (int c0 = 0; c0 < deg; c0 += 64){
    int C = min(64, deg - c0);
    int si = 0;
    float4 e4 = make_float4(-INFINITY,-INFINITY,-INFINITY,-INFINITY);
    if (lane < C){
      si = csr_src[b + c0 + lane];
      float4 l4 = *(const float4*)&el[si*4];
      e4.x = lrelu(l4.x + er4.x); e4.y = lrelu(l4.y + er4.y);
      e4.z = lrelu(l4.z + er4.z); e4.w = lrelu(l4.w + er4.w);
    }
    float4 mc = e4;
    #pragma unroll
    for (int off = 32; off; off >>= 1){
      mc.x = fmaxf(mc.x, __shfl_xor(mc.x, off));
      mc.y = fmaxf(mc.y, __shfl_xor(mc.y, off));
      mc.z = fmaxf(mc.z, __shfl_xor(mc.z, off));
      mc.w = fmaxf(mc.w, __shfl_xor(mc.w, off));
    }
    float4 mn; mn.x = fmaxf(m4.x, mc.x); mn.y = fmaxf(m4.y, mc.y);
    mn.z = fmaxf(m4.z, mc.z); mn.w = fmaxf(m4.w, mc.w);
    float4 sc; sc.x = __expf(m4.x - mn.x); sc.y = __expf(m4.y - mn.y);
    sc.z = __expf(m4.z - mn.z); sc.w = __expf(m4.w - mn.w);
    m4 = mn;
    float4 p4 = make_float4(0,0,0,0);
    if (lane < C){
      p4.x = __expf(e4.x - mn.x); p4.y = __expf(e4.y - mn.y);
      p4.z = __expf(e4.z - mn.z); p4.w = __expf(e4.w - mn.w);
    }
    float4 su = p4;
    #pragma unroll
    for (int off = 32; off; off >>= 1){
      su.x += __shfl_xor(su.x, off); su.y += __shfl_xor(su.y, off);
      su.z += __shfl_xor(su.z, off); su.w += __shfl_xor(su.w, off);
    }
    s4.x = s4.x*sc.x + su.x; s4.y = s4.y*sc.y + su.y;
    s4.z = s4.z*sc.z + su.z; s4.w = s4.w*sc.w + su.w;
    float asc = sel4(sc, h);
    acc.x *= asc; acc.y *= asc; acc.z *= asc; acc.w *= asc;
    *(float4*)&p_sh[w][lane*4] = p4;
    si_sh[w][lane] = si;
    #pragma unroll 4
    for (int j = 0; j < C; ++j){
      float a = p_sh[w][j*4 + h];
      int sj = si_sh[w][j];
      ushort4 u = *(const ushort4*)&featb[(size_t)sj*256 + lane*4];
      acc.x = fmaf(a, bf2f(u.x), acc.x); acc.y = fmaf(a, bf2f(u.y), acc.y);
      acc.z = fmaf(a, bf2f(u.z), acc.z); acc.w = fmaf(a, bf2f(u.w), acc.w);
    }
  }
  float4 o = make_float4(0,0,0,0);
  if (deg > 0){
    float rs = 1.0f / sel4(s4, h);
    o.x = acc.x * rs; o.y = acc.y * rs; o.z = acc.z * rs; o.w = acc.w * rs;
    o.x = o.x > 0.f ? o.x : expm1f(o.x);
    o.y = o.y > 0.f ? o.y : expm1f(o.y);
    o.z = o.z > 0.f ? o.z : expm1f(o.z);
    o.w = o.w > 0.f ? o.w : expm1f(o.w);
  }
  ushort4 ob = make_ushort4(f2bf(o.x), f2bf(o.y), f2bf(o.z), f2bf(o.w));
  *(ushort4*)&h1b[(size_t)n*256 + lane*4] = ob;
}

// ---------------- fused softmax+aggregate, layer 2 (fp32 gather) ----------------
__global__ __launch_bounds__(256) void k_fused2(
    const int* __restrict__ rowptr, const int* __restrict__ csr_src,
    const float* __restrict__ el, const float* __restrict__ er,
    const float* __restrict__ feat, float* __restrict__ out)
{
  __shared__ float p_sh[4][64];
  __shared__ int si_sh[4][64];
  int w = threadIdx.x >> 6, lane = threadIdx.x & 63;
  int n = blockIdx.x*4 + w;
  if (n >= NN) return;
  int b = rowptr[n], deg = rowptr[n+1] - b;
  float er_n = er[n];
  float m = -INFINITY, s = 0.f;
  float4 acc = make_float4(0,0,0,0);
  int half = lane >> 5, l32 = lane & 31;

  for (int c0 = 0; c0 < deg; c0 += 64){
    int C = min(64, deg - c0);
    int si = 0;
    float e = -INFINITY;
    if (lane < C){
      si = csr_src[b + c0 + lane];
      e = lrelu(el[si] + er_n);
    }
    float mc = e;
    #pragma unroll
    for (int off = 32; off; off >>= 1) mc = fmaxf(mc, __shfl_xor(mc, off));
    float mn = fmaxf(m, mc);
    float scl = __expf(m - mn);
    m = mn;
    float p = (lane < C) ? __expf(e - mn) : 0.f;
    float su = p;
    #pragma unroll
    for (int off = 32; off; off >>= 1) su += __shfl_xor(su, off);
    s = s*scl + su;
    acc.x *= scl; acc.y *= scl; acc.z *= scl; acc.w *= scl;
    p_sh[w][lane] = p;
    si_sh[w][lane] = si;
    int iters = (C + 1) >> 1;
    #pragma unroll 4
    for (int it = 0; it < iters; ++it){
      int e0 = 2*it + half;
      float a = p_sh[w][e0];
      int sj = si_sh[w][e0];
      float4 f = *(const float4*)&feat[(size_t)sj*128 + l32*4];
      acc.x = fmaf(a, f.x, acc.x); acc.y = fmaf(a, f.y, acc.y);
      acc.z = fmaf(a, f.z, acc.z); acc.w = fmaf(a, f.w, acc.w);
    }
  }
  acc.x += __shfl_xor(acc.x, 32); acc.y += __shfl_xor(acc.y, 32);
  acc.z += __shfl_xor(acc.z, 32); acc.w += __shfl_xor(acc.w, 32);
  if (lane < 32){
    float4 o = make_float4(0,0,0,0);
    if (deg > 0){
      float rs = 1.0f / s;
      o.x = acc.x*rs; o.y = acc.y*rs; o.z = acc.z*rs; o.w = acc.w*rs;
    }
    *(float4*)&out[(size_t)n*128 + l32*4] = o;
  }
}

// ---------------- host launch ----------------
static inline size_t align256(size_t x){ return (x + 255) & ~(size_t)255; }

extern "C" void kernel_launch(void* const* d_in, const int* in_sizes, int n_in,
                              void* d_out, int out_size, void* d_ws, size_t ws_size,
                              hipStream_t stream){
  const float* h_in = (const float*)d_in[0];
  const int*   src  = (const int*)d_in[1];
  const int*   dst  = (const int*)d_in[2];
  const float* W1   = (const float*)d_in[3];
  const float* al1  = (const float*)d_in[4];
  const float* ar1  = (const float*)d_in[5];
  const float* W2   = (const float*)d_in[6];
  const float* al2  = (const float*)d_in[7];
  const float* ar2  = (const float*)d_in[8];
  float* out = (float*)d_out;

  char* ws = (char*)d_ws;
  size_t off = 0;
  ushort* Ab     = (ushort*)(ws + off); off = align256(off + (size_t)NN*256*2);  // reused as h1b
  ushort* featb  = (ushort*)(ws + off); off = align256(off + (size_t)NN*256*2);
  float* feat2   = (float*)(ws + off);  off = align256(off + (size_t)NN*128*4);
  float* el1     = (float*)(ws + off);  off = align256(off + (size_t)NN*4*4);
  float* er1     = (float*)(ws + off);  off = align256(off + (size_t)NN*4*4);
  int* rowptr    = (int*)(ws + off);    off = align256(off + (size_t)(NN+1)*4);
  int* cnt       = (int*)(ws + off);    off = align256(off + (size_t)NN*4);
  int* cursor    = (int*)(ws + off);    off = align256(off + (size_t)NN*4);
  int* csr_src   = (int*)(ws + off);    off = align256(off + (size_t)EE*4);
  ushort* Bth1   = (ushort*)(ws + off); off = align256(off + (size_t)256*256*2);
  ushort* Btl1   = (ushort*)(ws + off); off = align256(off + (size_t)256*256*2);
  ushort* Bth2   = (ushort*)(ws + off); off = align256(off + (size_t)128*256*2);
  ushort* Btl2   = (ushort*)(ws + off); off = align256(off + (size_t)128*256*2);
  int* bsum      = (int*)(ws + off);    off = align256(off + (size_t)64*4);
  int* boff      = (int*)(ws + off);    off = align256(off + (size_t)64*4);
  if (off > ws_size) return;  // fail loudly: output stays poisoned

  ushort* h1b = Ab;   // safe alias: A-bf16 dead after GEMM1
  float* el2 = el1;   // reuse as float[NN]
  float* er2 = er1;

  const int EB = (EE + 255)/256;
  const int FB = (NN + 3)/4;
  const int NB = (NN + 1023)/1024;
  const int MT = (NN + 127)/128;

  // CSR build
  hipMemsetAsync(cnt, 0, (size_t)NN*4, stream);
  k_hist<<<EB, 256, 0, stream>>>(dst, cnt, EE);
  k_scan_bsum<<<NB, 1024, 0, stream>>>(cnt, bsum, NN);
  k_scan_boff<<<1, 64, 0, stream>>>(bsum, boff, NB, rowptr, NN);
  k_scan_write<<<NB, 1024, 0, stream>>>(cnt, boff, rowptr, NN);
  hipMemcpyAsync(cursor, rowptr, (size_t)NN*4, hipMemcpyDeviceToDevice, stream);
  k_scatter<<<EB, 256, 0, stream>>>(src, dst, cursor, csr_src, EE);

  // prep
  k_prepW<<<256, 256, 0, stream>>>(W1, Bth1, Btl1, 256, 256);
  k_prepW<<<256, 128, 0, stream>>>(W2, Bth2, Btl2, 256, 128);
  k_prepA<<<(NN*64 + 255)/256, 256, 0, stream>>>(h_in, Ab, NN*64);

  // ----- layer 1 -----
  k_mgemm<1><<<dim3(2, MT), 512, 0, stream>>>(Ab, Bth1, Btl1, featb, al1, ar1, el1, er1, NN, 256, 256);
  k_fused1<<<FB, 256, 0, stream>>>(rowptr, csr_src, el1, er1, featb, h1b);

  // ----- layer 2 -----
  k_mgemm<2><<<dim3(1, MT), 512, 0, stream>>>(h1b, Bth2, Btl2, feat2, al2, ar2, el2, er2, NN, 256, 128);
  k_fused2<<<FB, 256, 0, stream>>>(rowptr, csr_src, el2, er2, feat2, out);
}

// Round 8
// 257.835 us; speedup vs baseline: 3.4477x; 1.1100x over previous
//
#include <hip/hip_runtime.h>
#include <hip/hip_bf16.h>
#include <hip/hip_fp16.h>
#include <math.h>

#define NN 50000
#define EE 800000

__device__ __forceinline__ float lrelu(float v){ return v > 0.f ? v : 0.2f * v; }
__device__ __forceinline__ float sel4(float4 v, int h){
  return h == 0 ? v.x : h == 1 ? v.y : h == 2 ? v.z : v.w;
}
__device__ __forceinline__ ushort f2bf(float x){
  union { __hip_bfloat16 b; ushort u; } cv; cv.b = __float2bfloat16(x); return cv.u;
}
__device__ __forceinline__ float bf2f(ushort u){
  union { uint u; float f; } cv; cv.u = (uint)u << 16; return cv.f;
}
__device__ __forceinline__ ushort f2h(float x){
  union { __half h; ushort u; } cv; cv.h = __float2half(x); return cv.u;
}
__device__ __forceinline__ float h2f(ushort u){
  union { ushort u; __half h; } cv; cv.u = u; return __half2float(cv.h);
}

typedef __attribute__((ext_vector_type(8))) short bf16x8;
typedef __attribute__((ext_vector_type(4))) float f32x4;

// async global->LDS, 16B per lane
__device__ __forceinline__ void gload16(const ushort* g, ushort* l){
  const auto* gp = reinterpret_cast<const __attribute__((address_space(1))) ushort*>((size_t)g);
  auto* lp = reinterpret_cast<__attribute__((address_space(3))) ushort*>((size_t)l);
  __builtin_amdgcn_global_load_lds(gp, lp, 16, 0, 0);
}

// ---------------- CSR build ----------------
__global__ void k_hist(const int* __restrict__ dst, int* __restrict__ cnt, int E){
  int i = blockIdx.x * blockDim.x + threadIdx.x;
  if (i < E) atomicAdd(&cnt[dst[i]], 1);
}

__global__ __launch_bounds__(1024) void k_scan_bsum(const int* __restrict__ cnt, int* __restrict__ bsum, int n){
  __shared__ int ws[16];
  int t = threadIdx.x, i = blockIdx.x*1024 + t;
  int v = (i < n) ? cnt[i] : 0;
  #pragma unroll
  for (int off = 32; off; off >>= 1) v += __shfl_down(v, off);
  if ((t & 63) == 0) ws[t >> 6] = v;
  __syncthreads();
  if (t < 64){
    int x = (t < 16) ? ws[t] : 0;
    #pragma unroll
    for (int off = 32; off; off >>= 1) x += __shfl_down(x, off);
    if (t == 0) bsum[blockIdx.x] = x;
  }
}

__global__ void k_scan_boff(const int* __restrict__ bsum, int* __restrict__ boff,
                            int nb, int* __restrict__ rowptr, int n){
  int t = threadIdx.x;
  int v = (t < nb) ? bsum[t] : 0;
  int x = v;
  #pragma unroll
  for (int off = 1; off < 64; off <<= 1){ int y = __shfl_up(x, off); if (t >= off) x += y; }
  if (t < nb) boff[t] = x - v;
  if (t == 63) rowptr[n] = x;
}

__global__ __launch_bounds__(1024) void k_scan_write(const int* __restrict__ cnt, const int* __restrict__ boff,
                                                     int* __restrict__ rowptr, int* __restrict__ cursor, int n){
  __shared__ int ws[16];
  int t = threadIdx.x, w = t >> 6, lane = t & 63, i = blockIdx.x*1024 + t;
  int v = (i < n) ? cnt[i] : 0;
  int x = v;
  #pragma unroll
  for (int off = 1; off < 64; off <<= 1){ int y = __shfl_up(x, off); if (lane >= off) x += y; }
  if (lane == 63) ws[w] = x;
  __syncthreads();
  if (t < 16){
    int y = ws[t];
    #pragma unroll
    for (int off = 1; off < 16; off <<= 1){ int z = __shfl_up(y, off); if (t >= off) y += z; }
    ws[t] = y;
  }
  __syncthreads();
  if (i < n){
    int ex = boff[blockIdx.x] + ((w > 0) ? ws[w-1] : 0) + x - v;
    rowptr[i] = ex;
    cursor[i] = ex;
  }
}

__global__ void k_scatter(const int* __restrict__ src, const int* __restrict__ dst,
                          int* __restrict__ cursor, int* __restrict__ csr_src, int E){
  int i = blockIdx.x * blockDim.x + threadIdx.x;
  if (i < E){ int p = atomicAdd(&cursor[dst[i]], 1); csr_src[p] = src[i]; }
}

// ---------------- merged prep: A->bf16, W1/W2 -> transposed split-bf16 ----------------
// blocks [0,12500): prepA ; [12500,12756): W1 ; [12756,13012): W2
__global__ void k_prep(const float* __restrict__ A, ushort* __restrict__ Ab,
                       const float* __restrict__ W1, ushort* __restrict__ Bth1, ushort* __restrict__ Btl1,
                       const float* __restrict__ W2, ushort* __restrict__ Bth2, ushort* __restrict__ Btl2){
  int b = blockIdx.x, t = threadIdx.x;
  if (b < 12500){
    int i = b*256 + t;                       // i < 3,200,000 = NN*64 exactly
    float4 v = ((const float4*)A)[i];
    ((ushort4*)Ab)[i] = make_ushort4(f2bf(v.x), f2bf(v.y), f2bf(v.z), f2bf(v.w));
  } else if (b < 12756){
    int k = b - 12500;                       // 0..255
    float x = W1[(size_t)k*256 + t];
    ushort h = f2bf(x);
    Bth1[(size_t)t*256 + k] = h;
    Btl1[(size_t)t*256 + k] = f2bf(x - bf2f(h));
  } else {
    int k = b - 12756;                       // 0..255
    if (t < 128){
      float x = W2[(size_t)k*128 + t];
      ushort h = f2bf(x);
      Bth2[(size_t)t*256 + k] = h;
      Btl2[(size_t)t*256 + k] = f2bf(x - bf2f(h));
    }
  }
}

// ---------------- bf16-A x split-bf16-B MFMA GEMM + fused el/er epilogue ----------------
// MODE 1: Cout = bf16 featb (N=256, head = col/64, one wave per (row,head) -> direct el/er).
// MODE 2: Cout = f16 feat2 (N=128); 2 waves/row combine el/er partials via LDS.
template<int MODE>
__global__ __launch_bounds__(512, 4) void k_mgemm(
    const ushort* __restrict__ Ab,
    const ushort* __restrict__ Bth, const ushort* __restrict__ Btl,
    void* __restrict__ Cout, const float* __restrict__ avl, const float* __restrict__ avr,
    float* __restrict__ el, float* __restrict__ er, int M, int K, int N)
{
  __shared__ __align__(16) ushort sA[2][128*32];
  __shared__ __align__(16) ushort sBh[2][128*32];
  __shared__ __align__(16) ushort sBl[2][128*32];
  __shared__ float sEL[2][128], sER[2][128];   // MODE 2 combine
  int tid = threadIdx.x;
  int w = tid >> 6, lane = tid & 63;
  int bm = blockIdx.y*128, bn = blockIdx.x*128;
  int wm = (w & 3)*32, wn = (w >> 2)*64;
  int fr = lane & 15, fg = lane >> 4;

  int srow = 16*w + (lane >> 2);
  int skoff = (lane & 3)*8;
  int arow = bm + srow; if (arow > M-1) arow = M-1;       // clamp OOB (epilogue guards)
  const ushort* gA  = Ab  + (size_t)arow*K + skoff;
  const ushort* gBh = Bth + (size_t)(bn + srow)*K + skoff;
  const ushort* gBl = Btl + (size_t)(bn + srow)*K + skoff;
  int lslice = 16*w*32;

  const int nk = K >> 5;
  gload16(gA,  &sA[0][lslice]);
  gload16(gBh, &sBh[0][lslice]);
  gload16(gBl, &sBl[0][lslice]);
  __syncthreads();

  f32x4 acc[2][4] = {};
  for (int kt = 0; kt < nk; ++kt){
    int buf = kt & 1;
    if (kt + 1 < nk){
      int k1 = (kt + 1) << 5;
      gload16(gA + k1,  &sA[buf^1][lslice]);
      gload16(gBh + k1, &sBh[buf^1][lslice]);
      gload16(gBl + k1, &sBl[buf^1][lslice]);
    }
    bf16x8 ah[2], bh[4], bl[4];
    #pragma unroll
    for (int ti = 0; ti < 2; ++ti)
      ah[ti] = *(const bf16x8*)&sA[buf][(wm + ti*16 + fr)*32 + fg*8];
    #pragma unroll
    for (int tj = 0; tj < 4; ++tj){
      int bi = (wn + tj*16 + fr)*32 + fg*8;
      bh[tj] = *(const bf16x8*)&sBh[buf][bi];
      bl[tj] = *(const bf16x8*)&sBl[buf][bi];
    }
    #pragma unroll
    for (int ti = 0; ti < 2; ++ti)
      #pragma unroll
      for (int tj = 0; tj < 4; ++tj){
        acc[ti][tj] = __builtin_amdgcn_mfma_f32_16x16x32_bf16(ah[ti], bh[tj], acc[ti][tj], 0,0,0);
        acc[ti][tj] = __builtin_amdgcn_mfma_f32_16x16x32_bf16(ah[ti], bl[tj], acc[ti][tj], 0,0,0);
      }
    __syncthreads();
  }

  int colhead = bn + wn;
  float wl[4], wr[4];
  #pragma unroll
  for (int tj = 0; tj < 4; ++tj){
    int c = colhead + tj*16 + fr;
    wl[tj] = avl[c]; wr[tj] = avr[c];
  }
  #pragma unroll
  for (int ti = 0; ti < 2; ++ti)
    #pragma unroll
    for (int i = 0; i < 4; ++i){
      int row = bm + wm + ti*16 + fg*4 + i;
      float pl = 0.f, pr = 0.f;
      #pragma unroll
      for (int tj = 0; tj < 4; ++tj){
        float v = acc[ti][tj][i];
        pl = fmaf(v, wl[tj], pl);
        pr = fmaf(v, wr[tj], pr);
        if (row < M){
          int col = colhead + tj*16 + fr;
          if (MODE == 1) ((ushort*)Cout)[(size_t)row*256 + col] = f2bf(v);
          else           ((ushort*)Cout)[(size_t)row*128 + col] = f2h(v);
        }
      }
      #pragma unroll
      for (int mk = 1; mk < 16; mk <<= 1){
        pl += __shfl_xor(pl, mk);
        pr += __shfl_xor(pr, mk);
      }
      if (fr == 0){
        if (MODE == 1){
          if (row < M){ el[row*4 + (colhead >> 6)] = pl; er[row*4 + (colhead >> 6)] = pr; }
        } else {
          int lr = wm + ti*16 + fg*4 + i;
          sEL[w >> 2][lr] = pl; sER[w >> 2][lr] = pr;
        }
      }
    }
  if (MODE == 2){
    __syncthreads();
    if (tid < 128){
      int row = bm + tid;
      if (row < M){
        el[row] = sEL[0][tid] + sEL[1][tid];
        er[row] = sER[0][tid] + sER[1][tid];
      }
    }
  }
}

// ---------------- fused softmax+aggregate, layer 1 (bf16 gather, bf16 h1 out) ----------------
__global__ __launch_bounds__(256) void k_fused1(
    const int* __restrict__ rowptr, const int* __restrict__ csr_src,
    const float* __restrict__ el, const float* __restrict__ er,
    const ushort* __restrict__ featb, ushort* __restrict__ h1b)
{
  __shared__ __align__(16) float p_sh[4][64*4];
  __shared__ int si_sh[4][64];
  int w = threadIdx.x >> 6, lane = threadIdx.x & 63;
  int n = blockIdx.x*4 + w;
  if (n >= NN) return;
  int b = rowptr[n], deg = rowptr[n+1] - b;
  int h = lane >> 4;
  float4 er4 = *(const float4*)&er[n*4];
  float4 m4 = make_float4(-INFINITY,-INFINITY,-INFINITY,-INFINITY);
  float4 s4 = make_float4(0,0,0,0);
  float4 acc = make_float4(0,0,0,0);

  for (int c0 = 0; c0 < deg; c0 += 64){
    int C = min(64, deg - c0);
    int si = 0;
    float4 e4 = make_float4(-INFINITY,-INFINITY,-INFINITY,-INFINITY);
    if (lane < C){
      si = csr_src[b + c0 + lane];
      float4 l4 = *(const float4*)&el[si*4];
      e4.x = lrelu(l4.x + er4.x); e4.y = lrelu(l4.y + er4.y);
      e4.z = lrelu(l4.z + er4.z); e4.w = lrelu(l4.w + er4.w);
    }
    float4 mc = e4;
    #pragma unroll
    for (int off = 32; off; off >>= 1){
      mc.x = fmaxf(mc.x, __shfl_xor(mc.x, off));
      mc.y = fmaxf(mc.y, __shfl_xor(mc.y, off));
      mc.z = fmaxf(mc.z, __shfl_xor(mc.z, off));
      mc.w = fmaxf(mc.w, __shfl_xor(mc.w, off));
    }
    float4 mn; mn.x = fmaxf(m4.x, mc.x); mn.y = fmaxf(m4.y, mc.y);
    mn.z = fmaxf(m4.z, mc.z); mn.w = fmaxf(m4.w, mc.w);
    float4 sc; sc.x = __expf(m4.x - mn.x); sc.y = __expf(m4.y - mn.y);
    sc.z = __expf(m4.z - mn.z); sc.w = __expf(m4.w - mn.w);
    m4 = mn;
    float4 p4 = make_float4(0,0,0,0);
    if (lane < C){
      p4.x = __expf(e4.x - mn.x); p4.y = __expf(e4.y - mn.y);
      p4.z = __expf(e4.z - mn.z); p4.w = __expf(e4.w - mn.w);
    }
    float4 su = p4;
    #pragma unroll
    for (int off = 32; off; off >>= 1){
      su.x += __shfl_xor(su.x, off); su.y += __shfl_xor(su.y, off);
      su.z += __shfl_xor(su.z, off); su.w += __shfl_xor(su.w, off);
    }
    s4.x = s4.x*sc.x + su.x; s4.y = s4.y*sc.y + su.y;
    s4.z = s4.z*sc.z + su.z; s4.w = s4.w*sc.w + su.w;
    float asc = sel4(sc, h);
    acc.x *= asc; acc.y *= asc; acc.z *= asc; acc.w *= asc;
    *(float4*)&p_sh[w][lane*4] = p4;
    si_sh[w][lane] = si;
    #pragma unroll 4
    for (int j = 0; j < C; ++j){
      float a = p_sh[w][j*4 + h];
      int sj = si_sh[w][j];
      ushort4 u = *(const ushort4*)&featb[(size_t)sj*256 + lane*4];
      acc.x = fmaf(a, bf2f(u.x), acc.x); acc.y = fmaf(a, bf2f(u.y), acc.y);
      acc.z = fmaf(a, bf2f(u.z), acc.z); acc.w = fmaf(a, bf2f(u.w), acc.w);
    }
  }
  float4 o = make_float4(0,0,0,0);
  if (deg > 0){
    float rs = 1.0f / sel4(s4, h);
    o.x = acc.x * rs; o.y = acc.y * rs; o.z = acc.z * rs; o.w = acc.w * rs;
    o.x = o.x > 0.f ? o.x : expm1f(o.x);
    o.y = o.y > 0.f ? o.y : expm1f(o.y);
    o.z = o.z > 0.f ? o.z : expm1f(o.z);
    o.w = o.w > 0.f ? o.w : expm1f(o.w);
  }
  ushort4 ob = make_ushort4(f2bf(o.x), f2bf(o.y), f2bf(o.z), f2bf(o.w));
  *(ushort4*)&h1b[(size_t)n*256 + lane*4] = ob;
}

// ---------------- fused softmax+aggregate, layer 2 (f16 gather) ----------------
__global__ __launch_bounds__(256) void k_fused2(
    const int* __restrict__ rowptr, const int* __restrict__ csr_src,
    const float* __restrict__ el, const float* __restrict__ er,
    const ushort* __restrict__ featH, float* __restrict__ out)
{
  __shared__ float p_sh[4][64];
  __shared__ int si_sh[4][64];
  int w = threadIdx.x >> 6, lane = threadIdx.x & 63;
  int n = blockIdx.x*4 + w;
  if (n >= NN) return;
  int b = rowptr[n], deg = rowptr[n+1] - b;
  float er_n = er[n];
  float m = -INFINITY, s = 0.f;
  float4 acc = make_float4(0,0,0,0);
  int half = lane >> 5, l32 = lane & 31;

  for (int c0 = 0; c0 < deg; c0 += 64){
    int C = min(64, deg - c0);
    int si = 0;
    float e = -INFINITY;
    if (lane < C){
      si = csr_src[b + c0 + lane];
      e = lrelu(el[si] + er_n);
    }
    float mc = e;
    #pragma unroll
    for (int off = 32; off; off >>= 1) mc = fmaxf(mc, __shfl_xor(mc, off));
    float mn = fmaxf(m, mc);
    float scl = __expf(m - mn);
    m = mn;
    float p = (lane < C) ? __expf(e - mn) : 0.f;
    float su = p;
    #pragma unroll
    for (int off = 32; off; off >>= 1) su += __shfl_xor(su, off);
    s = s*scl + su;
    acc.x *= scl; acc.y *= scl; acc.z *= scl; acc.w *= scl;
    p_sh[w][lane] = p;
    si_sh[w][lane] = si;
    int iters = (C + 1) >> 1;
    #pragma unroll 4
    for (int it = 0; it < iters; ++it){
      int e0 = 2*it + half;
      float a = p_sh[w][e0];
      int sj = si_sh[w][e0];
      ushort4 u = *(const ushort4*)&featH[(size_t)sj*128 + l32*4];
      acc.x = fmaf(a, h2f(u.x), acc.x); acc.y = fmaf(a, h2f(u.y), acc.y);
      acc.z = fmaf(a, h2f(u.z), acc.z); acc.w = fmaf(a, h2f(u.w), acc.w);
    }
  }
  acc.x += __shfl_xor(acc.x, 32); acc.y += __shfl_xor(acc.y, 32);
  acc.z += __shfl_xor(acc.z, 32); acc.w += __shfl_xor(acc.w, 32);
  if (lane < 32){
    float4 o = make_float4(0,0,0,0);
    if (deg > 0){
      float rs = 1.0f / s;
      o.x = acc.x*rs; o.y = acc.y*rs; o.z = acc.z*rs; o.w = acc.w*rs;
    }
    *(float4*)&out[(size_t)n*128 + l32*4] = o;
  }
}

// ---------------- host launch ----------------
static inline size_t align256(size_t x){ return (x + 255) & ~(size_t)255; }

extern "C" void kernel_launch(void* const* d_in, const int* in_sizes, int n_in,
                              void* d_out, int out_size, void* d_ws, size_t ws_size,
                              hipStream_t stream){
  const float* h_in = (const float*)d_in[0];
  const int*   src  = (const int*)d_in[1];
  const int*   dst  = (const int*)d_in[2];
  const float* W1   = (const float*)d_in[3];
  const float* al1  = (const float*)d_in[4];
  const float* ar1  = (const float*)d_in[5];
  const float* W2   = (const float*)d_in[6];
  const float* al2  = (const float*)d_in[7];
  const float* ar2  = (const float*)d_in[8];
  float* out = (float*)d_out;

  char* ws = (char*)d_ws;
  size_t off = 0;
  ushort* Ab     = (ushort*)(ws + off); off = align256(off + (size_t)NN*256*2);  // reused as h1b
  ushort* featb  = (ushort*)(ws + off); off = align256(off + (size_t)NN*256*2);
  ushort* feat2  = (ushort*)(ws + off); off = align256(off + (size_t)NN*128*2);  // f16
  float* el1     = (float*)(ws + off);  off = align256(off + (size_t)NN*4*4);
  float* er1     = (float*)(ws + off);  off = align256(off + (size_t)NN*4*4);
  int* rowptr    = (int*)(ws + off);    off = align256(off + (size_t)(NN+1)*4);
  int* cnt       = (int*)(ws + off);    off = align256(off + (size_t)NN*4);
  int* cursor    = (int*)(ws + off);    off = align256(off + (size_t)NN*4);
  int* csr_src   = (int*)(ws + off);    off = align256(off + (size_t)EE*4);
  ushort* Bth1   = (ushort*)(ws + off); off = align256(off + (size_t)256*256*2);
  ushort* Btl1   = (ushort*)(ws + off); off = align256(off + (size_t)256*256*2);
  ushort* Bth2   = (ushort*)(ws + off); off = align256(off + (size_t)128*256*2);
  ushort* Btl2   = (ushort*)(ws + off); off = align256(off + (size_t)128*256*2);
  int* bsum      = (int*)(ws + off);    off = align256(off + (size_t)64*4);
  int* boff      = (int*)(ws + off);    off = align256(off + (size_t)64*4);
  if (off > ws_size) return;  // fail loudly: output stays poisoned

  ushort* h1b = Ab;   // safe alias: A-bf16 dead after GEMM1
  float* el2 = el1;   // reuse as float[NN]
  float* er2 = er1;

  const int EB = (EE + 255)/256;
  const int FB = (NN + 3)/4;
  const int NB = (NN + 1023)/1024;
  const int MT = (NN + 127)/128;

  // CSR build
  hipMemsetAsync(cnt, 0, (size_t)NN*4, stream);
  k_hist<<<EB, 256, 0, stream>>>(dst, cnt, EE);
  k_scan_bsum<<<NB, 1024, 0, stream>>>(cnt, bsum, NN);
  k_scan_boff<<<1, 64, 0, stream>>>(bsum, boff, NB, rowptr, NN);
  k_scan_write<<<NB, 1024, 0, stream>>>(cnt, boff, rowptr, cursor, NN);
  k_scatter<<<EB, 256, 0, stream>>>(src, dst, cursor, csr_src, EE);

  // merged prep: A->bf16 (12500 blocks) + W1 (256) + W2 (256)
  k_prep<<<13012, 256, 0, stream>>>(h_in, Ab, W1, Bth1, Btl1, W2, Bth2, Btl2);

  // ----- layer 1 -----
  k_mgemm<1><<<dim3(2, MT), 512, 0, stream>>>(Ab, Bth1, Btl1, featb, al1, ar1, el1, er1, NN, 256, 256);
  k_fused1<<<FB, 256, 0, stream>>>(rowptr, csr_src, el1, er1, featb, h1b);

  // ----- layer 2 -----
  k_mgemm<2><<<dim3(1, MT), 512, 0, stream>>>(h1b, Bth2, Btl2, feat2, al2, ar2, el2, er2, NN, 256, 128);
  k_fused2<<<FB, 256, 0, stream>>>(rowptr, csr_src, el2, er2, feat2, out);
}